// Round 12
// baseline (149.078 us; speedup 1.0000x reference)
//
#include <hip/hip_runtime.h>
#include <math.h>

typedef unsigned short u16;
typedef unsigned int u32;
typedef __bf16 bf16x8 __attribute__((ext_vector_type(8)));
typedef float f32x4 __attribute__((ext_vector_type(4)));
typedef unsigned short u16x8 __attribute__((ext_vector_type(8)));
typedef unsigned int u32x2 __attribute__((ext_vector_type(2)));

static __device__ __forceinline__ u16 f2bf(float f) {
  unsigned int u = __builtin_bit_cast(unsigned int, f);
  u = (u + 0x7FFFu + ((u >> 16) & 1u)) >> 16;
  return (u16)u;
}
static __device__ __forceinline__ float bf2f(u16 u) {
  unsigned int x = ((unsigned int)u) << 16;
  return __builtin_bit_cast(float, x);
}
static __device__ __forceinline__ u16 f2bfh(float f) {
  __bf16 b = (__bf16)f;
  return __builtin_bit_cast(u16, b);
}
static __device__ __forceinline__ void gll16(const u16* g, u16* l) {
  __builtin_amdgcn_global_load_lds((const __attribute__((address_space(1))) u32*)g,
                                   (__attribute__((address_space(3))) u32*)l, 16, 0, 0);
}

// ---------------- fused f32 -> bf16 convert for two buffers ----------------
__global__ __launch_bounds__(256) void cvt2_bf16(const float* __restrict__ a, u16* __restrict__ da, int n4a,
                                                 const float* __restrict__ b, u16* __restrict__ db, int n4b) {
  int idx = blockIdx.x * 256 + threadIdx.x;
  const float* src; u16* dst; int i;
  if (idx < n4a) { src = a; dst = da; i = idx; }
  else { i = idx - n4a; if (i >= n4b) return; src = b; dst = db; }
  float4 v = ((const float4*)src)[i];
  ushort4 r;
  r.x = f2bf(v.x); r.y = f2bf(v.y); r.z = f2bf(v.z); r.w = f2bf(v.w);
  ((ushort4*)dst)[i] = r;
}

// ---------------- bf16 NT GEMM, m97 structure: gll16 staging, linear LDS + swizzled src ----
__global__ __launch_bounds__(256) void gemm_nt(const u16* __restrict__ A, const u16* __restrict__ B,
                                               float* __restrict__ C, int M, int N, int K) {
  __shared__ __align__(16) u16 sA[128 * 32];
  __shared__ __align__(16) u16 sB[128 * 32];
  const int tid = threadIdx.x;
  const int w = tid >> 6, lane = tid & 63, l15 = lane & 15;
  const int m0 = blockIdx.x * 128, n0 = blockIdx.y * 128;
  const int wm = (w >> 1) * 64, wn = (w & 1) * 64;

  f32x4 acc[4][4] = {};

  const int pb0 = w * 1024 + lane * 16;
  int srow[2], scol[2];
#pragma unroll
  for (int i = 0; i < 2; ++i) {
    int p = pb0 + i * 4096;
    int row = p >> 6, oo = p & 63;
    int ol = oo ^ (((row >> 1) & 3) << 4);
    srow[i] = row; scol[i] = ol >> 1;
  }
  int aoff[4], boff[4];
  const int kb = (lane >> 4) * 16;
#pragma unroll
  for (int m = 0; m < 4; ++m) {
    int r = wm + m * 16 + l15;
    aoff[m] = r * 64 + (kb ^ (((r >> 1) & 3) << 4));
  }
#pragma unroll
  for (int n = 0; n < 4; ++n) {
    int r = wn + n * 16 + l15;
    boff[n] = r * 64 + (kb ^ (((r >> 1) & 3) << 4));
  }

  for (int k0 = 0; k0 < K; k0 += 32) {
#pragma unroll
    for (int i = 0; i < 2; ++i) {
      int p = pb0 + i * 4096;
      gll16(A + (size_t)(m0 + srow[i]) * K + k0 + scol[i], (u16*)((char*)sA + p));
      gll16(B + (size_t)(n0 + srow[i]) * K + k0 + scol[i], (u16*)((char*)sB + p));
    }
    __syncthreads();
    bf16x8 af[4], bfr[4];
#pragma unroll
    for (int m = 0; m < 4; ++m) af[m] = *(const bf16x8*)((const char*)sA + aoff[m]);
#pragma unroll
    for (int n = 0; n < 4; ++n) bfr[n] = *(const bf16x8*)((const char*)sB + boff[n]);
#pragma unroll
    for (int m = 0; m < 4; ++m)
#pragma unroll
      for (int n = 0; n < 4; ++n)
        acc[m][n] = __builtin_amdgcn_mfma_f32_16x16x32_bf16(af[m], bfr[n], acc[m][n], 0, 0, 0);
    __syncthreads();
  }

#pragma unroll
  for (int m = 0; m < 4; ++m)
#pragma unroll
    for (int i = 0; i < 4; ++i) {
      int gr = m0 + wm + m * 16 + (lane >> 4) * 4 + i;
      float* crow = C + (size_t)gr * N + n0 + wn + l15;
#pragma unroll
      for (int n = 0; n < 4; ++n) crow[n * 16] = acc[m][n][i];
    }
}

// ---------------- RMSNorm + RoPE + V cast + gate ----------------
#define QSCALE 0.18033688011112042f
__global__ __launch_bounds__(256) void norm_rope_gate(const float* __restrict__ qkv, const float* __restrict__ x,
                                                      const float* __restrict__ qw, const float* __restrict__ kw,
                                                      const float* __restrict__ gw,
                                                      u16* __restrict__ Q, u16* __restrict__ Kd,
                                                      u16* __restrict__ V, float* __restrict__ gate) {
  const int t = blockIdx.x * 4 + (threadIdx.x >> 6);
  const int lane = threadIdx.x & 63;
  const int b = t >> 11, s = t & 2047;
  const float* base = qkv + (size_t)t * 1536;
  const int ri = lane >> 1;
  float sn, cs;
  sincosf((float)s * expf(-(float)ri * (9.21034037198f / 32.0f)), &sn, &cs);
  const float qwl = qw[lane], kwl = kw[lane];

#pragma unroll 4
  for (int hh = 0; hh < 16; ++hh) {
    float v = base[hh * 64 + lane];
    float ss = v * v;
#pragma unroll
    for (int off = 32; off >= 1; off >>= 1) ss += __shfl_xor(ss, off);
    float r = rsqrtf(ss * (1.0f / 64.0f) + 1.1920929e-7f);
    float xn = v * r * qwl;
    float p = __shfl_xor(xn, 1);
    float outv = ((lane & 1) == 0) ? (xn * cs - p * sn) : (xn * cs + p * sn);
    Q[((size_t)(b * 16 + hh) * 2048 + s) * 64 + lane] = f2bf(outv * QSCALE);
  }
#pragma unroll
  for (int hh = 0; hh < 4; ++hh) {
    float v = base[1024 + hh * 64 + lane];
    float ss = v * v;
#pragma unroll
    for (int off = 32; off >= 1; off >>= 1) ss += __shfl_xor(ss, off);
    float r = rsqrtf(ss * (1.0f / 64.0f) + 1.1920929e-7f);
    float xn = v * r * kwl;
    float p = __shfl_xor(xn, 1);
    float outv = ((lane & 1) == 0) ? (xn * cs - p * sn) : (xn * cs + p * sn);
    Kd[((size_t)(b * 4 + hh) * 2048 + s) * 64 + lane] = f2bf(outv);
    V[((size_t)(b * 4 + hh) * 2048 + s) * 64 + lane] = f2bf(base[1280 + hh * 64 + lane]);
  }
  if (lane < 16) {
    float g = 0.f;
#pragma unroll
    for (int j = 0; j < 12; ++j) g += x[(size_t)t * 1024 + j] * gw[lane * 12 + j];
    gate[(size_t)t * 16 + lane] = 1.0f / (1.0f + __expf(-g));
  }
}

// ---------------- V transpose: [bh][s][d] -> [bh][d][s] ----------------
__global__ __launch_bounds__(256) void transpose_v64(const u16* __restrict__ V, u16* __restrict__ Vt) {
  __shared__ __align__(16) u16 tile[64][72];
  const int st = blockIdx.x, bh = blockIdx.y;
  const u16* src = V + ((size_t)bh * 2048 + st * 64) * 64;
  u16* dst = Vt + (size_t)bh * 64 * 2048 + st * 64;
  const int t = threadIdx.x;
  const int r = t >> 2, c0 = (t & 3) * 16;
#pragma unroll
  for (int j = 0; j < 2; ++j)
    *(u16x8*)&tile[r][c0 + j * 8] = *(const u16x8*)&src[(size_t)r * 64 + c0 + j * 8];
  __syncthreads();
  u16 tmp[16];
#pragma unroll
  for (int j = 0; j < 16; ++j) tmp[j] = tile[c0 + j][r];
#pragma unroll
  for (int j = 0; j < 2; ++j)
    *(u16x8*)&dst[(size_t)r * 2048 + c0 + j * 8] = *(const u16x8*)&tmp[j * 8];
}

// ---------------- Flash attention: 4 streams/wave (2 q-tiles x 2 GQA heads), z=2 -----
// grid (16, 16, 2). Block (x, bhp, z): b=bhp>>3, head pair (2*hp, 2*hp+1) sharing kvh;
// q-tiles qiA=x, qiB=31-x; KV tiles t ≡ z (mod 2). One K/V staging (gll16, linear dest
// + pre-swizzled source) feeds 4 independent softmax/PV chains per wave. No-max softmax.
__global__ __launch_bounds__(256) void attn_fwd_pair(const u16* __restrict__ Q, const u16* __restrict__ Kg,
                                                     const u16* __restrict__ Vt,
                                                     u16* __restrict__ accP, float* __restrict__ lP) {
  __shared__ __align__(16) u16 sK[2][64 * 64];  // K[kv][d], double-buffered, swizzled
  __shared__ __align__(16) u16 sV[2][64 * 64];  // Vt[d][kv], swizzled
  __shared__ __align__(16) u16 sP[4][16 * 64];  // per-wave P[q][kv], swizzled (streams serialized)

  const int tid = threadIdx.x;
  const int w = tid >> 6, lane = tid & 63;
  const int l15 = lane & 15, lg = lane >> 4;
  const int qiA = blockIdx.x;          // 0..15
  const int qiB = 31 - qiA;            // 31..16
  const int z = blockIdx.z;            // 0..1
  const int bhp = blockIdx.y, b = bhp >> 3, hp = bhp & 7, kvh = hp >> 1;
  const int h0 = hp * 2;

  const u16* Kp = Kg + (size_t)(b * 4 + kvh) * 2048 * 64;
  const u16* Vp = Vt + (size_t)(b * 4 + kvh) * 64 * 2048;

  const int q0s[2] = {qiA * 64, qiB * 64};
  bf16x8 qa[4][2];
#pragma unroll
  for (int s = 0; s < 4; ++s) {
    const u16* qrow = Q + ((size_t)(b * 16 + h0 + (s & 1)) * 2048 + q0s[s >> 1] + w * 16 + l15) * 64 + lg * 8;
    qa[s][0] = *(const bf16x8*)qrow;
    qa[s][1] = *(const bf16x8*)(qrow + 32);
  }

  f32x4 acc[4][4] = {};
  float l_s[4] = {0.f, 0.f, 0.f, 0.f};

  // gll16 staging: LDS linear (wave base + lane*16), global source pre-swizzled.
  int koff[2], voff[2], ldso[2];
#pragma unroll
  for (int i = 0; i < 2; ++i) {
    int p = w * 1024 + i * 4096 + lane * 16;
    int row = p >> 7, gcol = (p & 127) >> 4;
    int sg = gcol ^ (row & 7);
    ldso[i] = p;
    koff[i] = row * 64 + sg * 8;      // K: row-major [kv][64]
    voff[i] = row * 2048 + sg * 8;    // Vt: row-major [d][2048]
  }

  // fragment read byte offsets (swizzle row&7 == l15&7 for rows ct*16+l15)
  const int swzF = (l15 & 7) << 4;
  const int fo0 = (lg * 16) ^ swzF;
  const int fo1 = (64 + lg * 16) ^ swzF;
  const int swzP = swzF;
  char* prow = (char*)sP[w] + l15 * 128;

  // prologue: stage tile z into buffer 0
#pragma unroll
  for (int i = 0; i < 2; ++i) {
    gll16(Kp + (size_t)z * 4096 + koff[i], (u16*)((char*)sK[0] + ldso[i]));
    gll16(Vp + z * 64 + voff[i], (u16*)((char*)sV[0] + ldso[i]));
  }
  __syncthreads();

  int it = 0;
  for (int t = z; t <= qiB; t += 2, ++it) {
    const int buf = it & 1;

    // async prefetch of tile t+2 into the other buffer; lands by the end-of-iter barrier
    if (t + 2 <= qiB) {
#pragma unroll
      for (int i = 0; i < 2; ++i) {
        gll16(Kp + (size_t)(t + 2) * 4096 + koff[i], (u16*)((char*)sK[buf ^ 1] + ldso[i]));
        gll16(Vp + (t + 2) * 64 + voff[i], (u16*)((char*)sV[buf ^ 1] + ldso[i]));
      }
    }

    // shared K / V fragments (read once, used by all 4 streams)
    bf16x8 kf[4][2], vf[4][2];
#pragma unroll
    for (int ct = 0; ct < 4; ++ct) {
      const char* krow = (const char*)sK[buf] + (ct * 16 + l15) * 128;
      const char* vrow = (const char*)sV[buf] + (ct * 16 + l15) * 128;
      kf[ct][0] = *(const bf16x8*)(krow + fo0);
      kf[ct][1] = *(const bf16x8*)(krow + fo1);
      vf[ct][0] = *(const bf16x8*)(vrow + fo0);
      vf[ct][1] = *(const bf16x8*)(vrow + fo1);
    }

#pragma unroll
    for (int s = 0; s < 4; ++s) {
      if ((s >> 1) == 0 && t > qiA) continue;   // q-tile A streams done (uniform branch)
      const int diag = (s >> 1) ? qiB : qiA;

      // S^T = K Q^T: lane holds S[kv=ct*16+lg*4+i][q=l15]
      f32x4 st[4];
#pragma unroll
      for (int ct = 0; ct < 4; ++ct) {
        f32x4 s4 = {};
        s4 = __builtin_amdgcn_mfma_f32_16x16x32_bf16(kf[ct][0], qa[s][0], s4, 0, 0, 0);
        s4 = __builtin_amdgcn_mfma_f32_16x16x32_bf16(kf[ct][1], qa[s][1], s4, 0, 0, 0);
        st[ct] = s4;
      }

      if (t == diag) {
        const int ql = w * 16 + l15;
#pragma unroll
        for (int ct = 0; ct < 4; ++ct)
#pragma unroll
          for (int i = 0; i < 4; ++i)
            st[ct][i] = (ct * 16 + lg * 4 + i <= ql) ? st[ct][i] : -1e30f;
      }

      // P = exp2(S'), pack pairs, accumulate per-lane row-sum (q=l15)
      float ls = 0.f;
#pragma unroll
      for (int ct = 0; ct < 4; ++ct) {
        float p0 = exp2f(st[ct][0]), p1 = exp2f(st[ct][1]);
        float p2 = exp2f(st[ct][2]), p3 = exp2f(st[ct][3]);
        ls += (p0 + p1) + (p2 + p3);
        u32 lo = (u32)f2bfh(p0) | ((u32)f2bfh(p1) << 16);
        u32 hi = (u32)f2bfh(p2) | ((u32)f2bfh(p3) << 16);
        *(u32x2*)(prow + ((ct * 32 + lg * 8) ^ swzP)) = (u32x2){lo, hi};
      }
      l_s[s] += ls;

      // read P as A-fragments (wave-internal; compiler-ordered lgkmcnt)
      bf16x8 pa0 = *(const bf16x8*)(prow + ((lg * 16) ^ swzP));
      bf16x8 pa1 = *(const bf16x8*)(prow + ((64 + lg * 16) ^ swzP));

#pragma unroll
      for (int n = 0; n < 4; ++n) {
        acc[s][n] = __builtin_amdgcn_mfma_f32_16x16x32_bf16(pa0, vf[n][0], acc[s][n], 0, 0, 0);
        acc[s][n] = __builtin_amdgcn_mfma_f32_16x16x32_bf16(pa1, vf[n][1], acc[s][n], 0, 0, 0);
      }
    }

    __syncthreads();   // prefetched tile landed (vmcnt drain) + all waves done with buf
  }

  // epilogue: reduce l across lg-groups, write unnormalized partials for all 4 streams.
#pragma unroll
  for (int s = 0; s < 4; ++s) {
    const int hs = h0 + (s & 1);
    const int q0 = q0s[s >> 1];
    float lv = l_s[s];
    lv += __shfl_xor(lv, 16);
    lv += __shfl_xor(lv, 32);
    if (lg == 0) {
      int qrow = q0 + w * 16 + l15;
      lP[((size_t)z * 4096 + b * 2048 + qrow) * 16 + hs] = lv;
    }
#pragma unroll
    for (int i = 0; i < 4; ++i) {
      int srowg = q0 + w * 16 + lg * 4 + i;
      size_t rowbase = (size_t)z * 4096 + b * 2048 + srowg;
      u16* orow = accP + rowbase * 1024 + hs * 64 + l15;
#pragma unroll
      for (int n = 0; n < 4; ++n) orow[n * 16] = f2bfh(acc[s][n][i]);
    }
  }
}

// ---------------- combine KV-split partials: O = (a0+a1)/(l0+l1) * gate ----------------
__global__ __launch_bounds__(256) void attn_combine(const u16* __restrict__ accP, const float* __restrict__ lP,
                                                    const float* __restrict__ gate, u16* __restrict__ attnh) {
  const size_t e = ((size_t)blockIdx.x * 256 + threadIdx.x) * 8;
  const int token = (int)(e >> 10);
  const int h = (int)((e >> 6) & 15);
  u16x8 a0 = *(const u16x8*)(accP + e);
  u16x8 a1 = *(const u16x8*)(accP + ((size_t)4096 << 10) + e);
  const size_t li = (size_t)token * 16 + h;
  float l = lP[li] + lP[(size_t)4096 * 16 + li];
  float g = gate[li] / l;
  u16x8 o;
#pragma unroll
  for (int j = 0; j < 8; ++j) o[j] = f2bfh((bf2f(a0[j]) + bf2f(a1[j])) * g);
  *(u16x8*)(attnh + e) = o;
}

// ---------------- launch ----------------
extern "C" void kernel_launch(void* const* d_in, const int* in_sizes, int n_in,
                              void* d_out, int out_size, void* d_ws, size_t ws_size,
                              hipStream_t stream) {
  const float* x  = (const float*)d_in[0];
  const float* Wf = (const float*)d_in[1];
  const float* qw = (const float*)d_in[2];
  const float* kw = (const float*)d_in[3];
  const float* gw = (const float*)d_in[4];
  float* out = (float*)d_out;

  char* ws = (char*)d_ws;
  size_t off = 0;
  auto alloc = [&](size_t bytes) { void* p = ws + off; off += (bytes + 255) & ~(size_t)255; return p; };

  u16*   xb   = (u16*)alloc((size_t)4096 * 1024 * 2);
  u16*   wb   = (u16*)alloc((size_t)2560 * 1024 * 2);
  float* qkv  = (float*)alloc((size_t)4096 * 1536 * 4);
  u16*   Qb   = (u16*)alloc((size_t)2 * 16 * 2048 * 64 * 2);
  u16*   Kb   = (u16*)alloc((size_t)2 * 4 * 2048 * 64 * 2);
  u16*   Vb   = (u16*)alloc((size_t)2 * 4 * 2048 * 64 * 2);
  u16*   Vtb  = (u16*)alloc((size_t)2 * 4 * 2048 * 64 * 2);
  float* gate = (float*)alloc((size_t)2 * 2048 * 16 * 4);
  float* lP   = (float*)alloc((size_t)2 * 4096 * 16 * 4);
  // partial acc (2 zones x 8 MB) aliases qkv (24 MB, dead after norm_rope_gate);
  // attnh (8 MB) aliases xb (dead after the QKV GEMM).
  u16* accP  = (u16*)qkv;
  u16* attnh = xb;

  cvt2_bf16<<<dim3(6656), dim3(256), 0, stream>>>(x, xb, 4096 * 1024 / 4, Wf, wb, 2560 * 1024 / 4);
  gemm_nt<<<dim3(32, 12), dim3(256), 0, stream>>>(xb, wb, qkv, 4096, 1536, 1024);
  norm_rope_gate<<<dim3(1024), dim3(256), 0, stream>>>(qkv, x, qw, kw, gw, Qb, Kb, Vb, gate);
  transpose_v64<<<dim3(32, 8), dim3(256), 0, stream>>>(Vb, Vtb);
  attn_fwd_pair<<<dim3(16, 16, 2), dim3(256), 0, stream>>>(Qb, Kb, Vtb, accP, lP);
  attn_combine<<<dim3(2048), dim3(256), 0, stream>>>(accP, lP, gate, attnh);
  gemm_nt<<<dim3(32, 8), dim3(256), 0, stream>>>(attnh, wb + (size_t)1536 * 1024, out, 4096, 1024, 1024);
}

// Round 13
// 129.844 us; speedup vs baseline: 1.1481x; 1.1481x over previous
//
#include <hip/hip_runtime.h>
#include <math.h>

typedef unsigned short u16;
typedef unsigned int u32;
typedef __bf16 bf16x8 __attribute__((ext_vector_type(8)));
typedef float f32x4 __attribute__((ext_vector_type(4)));
typedef unsigned short u16x8 __attribute__((ext_vector_type(8)));
typedef unsigned int u32x2 __attribute__((ext_vector_type(2)));

static __device__ __forceinline__ u16 f2bf(float f) {
  unsigned int u = __builtin_bit_cast(unsigned int, f);
  u = (u + 0x7FFFu + ((u >> 16) & 1u)) >> 16;
  return (u16)u;
}
static __device__ __forceinline__ float bf2f(u16 u) {
  unsigned int x = ((unsigned int)u) << 16;
  return __builtin_bit_cast(float, x);
}
static __device__ __forceinline__ u16 f2bfh(float f) {
  __bf16 b = (__bf16)f;
  return __builtin_bit_cast(u16, b);
}
static __device__ __forceinline__ void gll16(const u16* g, u16* l) {
  __builtin_amdgcn_global_load_lds((const __attribute__((address_space(1))) u32*)g,
                                   (__attribute__((address_space(3))) u32*)l, 16, 0, 0);
}

#define QSCALE 0.18033688011112042f

// ---------------- fused f32 -> bf16 convert for two buffers ----------------
__global__ __launch_bounds__(256) void cvt2_bf16(const float* __restrict__ a, u16* __restrict__ da, int n4a,
                                                 const float* __restrict__ b, u16* __restrict__ db, int n4b) {
  int idx = blockIdx.x * 256 + threadIdx.x;
  const float* src; u16* dst; int i;
  if (idx < n4a) { src = a; dst = da; i = idx; }
  else { i = idx - n4a; if (i >= n4b) return; src = b; dst = db; }
  float4 v = ((const float4*)src)[i];
  ushort4 r;
  r.x = f2bf(v.x); r.y = f2bf(v.y); r.z = f2bf(v.z); r.w = f2bf(v.w);
  ((ushort4*)dst)[i] = r;
}

// ---------------- RoPE cos/sin table: tab[s][j] = (cos, sin), j = d>>1 ----------------
__global__ __launch_bounds__(256) void rope_tab_k(float2* __restrict__ tab) {
  int idx = blockIdx.x * 256 + threadIdx.x;   // 2048*32 entries
  int s = idx >> 5, j = idx & 31;
  float sn, cs;
  sincosf((float)s * expf(-(float)j * (9.21034037198f / 32.0f)), &sn, &cs);
  tab[idx] = make_float2(cs, sn);
}

// ---------------- bf16 NT GEMM, m97 structure (out-proj) ----------------
__global__ __launch_bounds__(256) void gemm_nt(const u16* __restrict__ A, const u16* __restrict__ B,
                                               float* __restrict__ C, int M, int N, int K) {
  __shared__ __align__(16) u16 sA[128 * 32];
  __shared__ __align__(16) u16 sB[128 * 32];
  const int tid = threadIdx.x;
  const int w = tid >> 6, lane = tid & 63, l15 = lane & 15;
  const int m0 = blockIdx.x * 128, n0 = blockIdx.y * 128;
  const int wm = (w >> 1) * 64, wn = (w & 1) * 64;

  f32x4 acc[4][4] = {};

  const int pb0 = w * 1024 + lane * 16;
  int srow[2], scol[2];
#pragma unroll
  for (int i = 0; i < 2; ++i) {
    int p = pb0 + i * 4096;
    int row = p >> 6, oo = p & 63;
    int ol = oo ^ (((row >> 1) & 3) << 4);
    srow[i] = row; scol[i] = ol >> 1;
  }
  int aoff[4], boff[4];
  const int kb = (lane >> 4) * 16;
#pragma unroll
  for (int m = 0; m < 4; ++m) {
    int r = wm + m * 16 + l15;
    aoff[m] = r * 64 + (kb ^ (((r >> 1) & 3) << 4));
  }
#pragma unroll
  for (int n = 0; n < 4; ++n) {
    int r = wn + n * 16 + l15;
    boff[n] = r * 64 + (kb ^ (((r >> 1) & 3) << 4));
  }

  for (int k0 = 0; k0 < K; k0 += 32) {
#pragma unroll
    for (int i = 0; i < 2; ++i) {
      int p = pb0 + i * 4096;
      gll16(A + (size_t)(m0 + srow[i]) * K + k0 + scol[i], (u16*)((char*)sA + p));
      gll16(B + (size_t)(n0 + srow[i]) * K + k0 + scol[i], (u16*)((char*)sB + p));
    }
    __syncthreads();
    bf16x8 af[4], bfr[4];
#pragma unroll
    for (int m = 0; m < 4; ++m) af[m] = *(const bf16x8*)((const char*)sA + aoff[m]);
#pragma unroll
    for (int n = 0; n < 4; ++n) bfr[n] = *(const bf16x8*)((const char*)sB + boff[n]);
#pragma unroll
    for (int m = 0; m < 4; ++m)
#pragma unroll
      for (int n = 0; n < 4; ++n)
        acc[m][n] = __builtin_amdgcn_mfma_f32_16x16x32_bf16(af[m], bfr[n], acc[m][n], 0, 0, 0);
    __syncthreads();
  }

#pragma unroll
  for (int m = 0; m < 4; ++m)
#pragma unroll
    for (int i = 0; i < 4; ++i) {
      int gr = m0 + wm + m * 16 + (lane >> 4) * 4 + i;
      float* crow = C + (size_t)gr * N + n0 + wn + l15;
#pragma unroll
      for (int n = 0; n < 4; ++n) crow[n * 16] = acc[m][n][i];
    }
}

// ---------------- QKV GEMM with fused RMSNorm+RoPE epilogue ----------------
// N = 1536: wave tile (64 tokens x 64 cols) = exactly one head. he = (n0+wn)>>6:
// he<16 -> Q head (norm+rope, *QSCALE); he<20 -> K head (norm+rope); else V (cast).
__global__ __launch_bounds__(256) void gemm_qkv(const u16* __restrict__ A, const u16* __restrict__ B,
                                                const float* __restrict__ qw, const float* __restrict__ kw,
                                                const float2* __restrict__ tab,
                                                u16* __restrict__ Qo, u16* __restrict__ Ko,
                                                u16* __restrict__ Vo, int K) {
  __shared__ __align__(16) u16 sA[128 * 32];
  __shared__ __align__(16) u16 sB[128 * 32];
  const int tid = threadIdx.x;
  const int w = tid >> 6, lane = tid & 63, l15 = lane & 15, lg = lane >> 4;
  const int m0 = blockIdx.x * 128, n0 = blockIdx.y * 128;
  const int wm = (w >> 1) * 64, wn = (w & 1) * 64;

  f32x4 acc[4][4] = {};

  const int pb0 = w * 1024 + lane * 16;
  int srow[2], scol[2];
#pragma unroll
  for (int i = 0; i < 2; ++i) {
    int p = pb0 + i * 4096;
    int row = p >> 6, oo = p & 63;
    int ol = oo ^ (((row >> 1) & 3) << 4);
    srow[i] = row; scol[i] = ol >> 1;
  }
  int aoff[4], boff[4];
  const int kb = lg * 16;
#pragma unroll
  for (int m = 0; m < 4; ++m) {
    int r = wm + m * 16 + l15;
    aoff[m] = r * 64 + (kb ^ (((r >> 1) & 3) << 4));
  }
#pragma unroll
  for (int n = 0; n < 4; ++n) {
    int r = wn + n * 16 + l15;
    boff[n] = r * 64 + (kb ^ (((r >> 1) & 3) << 4));
  }

  for (int k0 = 0; k0 < K; k0 += 32) {
#pragma unroll
    for (int i = 0; i < 2; ++i) {
      int p = pb0 + i * 4096;
      gll16(A + (size_t)(m0 + srow[i]) * K + k0 + scol[i], (u16*)((char*)sA + p));
      gll16(B + (size_t)(n0 + srow[i]) * K + k0 + scol[i], (u16*)((char*)sB + p));
    }
    __syncthreads();
    bf16x8 af[4], bfr[4];
#pragma unroll
    for (int m = 0; m < 4; ++m) af[m] = *(const bf16x8*)((const char*)sA + aoff[m]);
#pragma unroll
    for (int n = 0; n < 4; ++n) bfr[n] = *(const bf16x8*)((const char*)sB + boff[n]);
#pragma unroll
    for (int m = 0; m < 4; ++m)
#pragma unroll
      for (int n = 0; n < 4; ++n)
        acc[m][n] = __builtin_amdgcn_mfma_f32_16x16x32_bf16(af[m], bfr[n], acc[m][n], 0, 0, 0);
    __syncthreads();
  }

  // ---- fused epilogue ----
  const int he = (n0 + wn) >> 6;   // wave-uniform head index 0..23
  if (he < 20) {
    // Q or K: RMSNorm over the head dim (64 cols) + interleaved RoPE
    const float* wnorm = (he < 16) ? qw : kw;
    const float oscale = (he < 16) ? QSCALE : 1.0f;
    float wv[4];
#pragma unroll
    for (int n = 0; n < 4; ++n) wv[n] = wnorm[n * 16 + l15];
    float2 tj[4];
#pragma unroll
    for (int m = 0; m < 4; ++m)
#pragma unroll
      for (int i = 0; i < 4; ++i) {
        const int gr = m0 + wm + m * 16 + lg * 4 + i;
        const int s = gr & 2047, bb = gr >> 11;
        // row sum of squares: 4 regs + shfl reduce across the 16-lane col group
        float ss = 0.f;
#pragma unroll
        for (int n = 0; n < 4; ++n) ss += acc[m][n][i] * acc[m][n][i];
        ss += __shfl_xor(ss, 8); ss += __shfl_xor(ss, 4);
        ss += __shfl_xor(ss, 2); ss += __shfl_xor(ss, 1);
        const float r = rsqrtf(ss * (1.0f / 64.0f) + 1.1920929e-7f);
#pragma unroll
        for (int n = 0; n < 4; ++n) tj[n] = tab[s * 32 + n * 8 + (l15 >> 1)];
        u16* orow = (he < 16)
          ? Qo + ((size_t)(bb * 16 + he) * 2048 + s) * 64 + l15
          : Ko + ((size_t)(bb * 4 + (he - 16)) * 2048 + s) * 64 + l15;
#pragma unroll
        for (int n = 0; n < 4; ++n) {
          float xn = acc[m][n][i] * r * wv[n];
          float p = __shfl_xor(xn, 1);
          float outv = ((l15 & 1) == 0) ? (xn * tj[n].x - p * tj[n].y)
                                        : (xn * tj[n].x + p * tj[n].y);
          orow[n * 16] = f2bf(outv * oscale);
        }
      }
  } else {
    // V: plain bf16 cast
#pragma unroll
    for (int m = 0; m < 4; ++m)
#pragma unroll
      for (int i = 0; i < 4; ++i) {
        const int gr = m0 + wm + m * 16 + lg * 4 + i;
        const int s = gr & 2047, bb = gr >> 11;
        u16* orow = Vo + ((size_t)(bb * 4 + (he - 20)) * 2048 + s) * 64 + l15;
#pragma unroll
        for (int n = 0; n < 4; ++n) orow[n * 16] = f2bf(acc[m][n][i]);
      }
  }
}

// ---------------- V transpose: [bh][s][d] -> [bh][d][s] ----------------
__global__ __launch_bounds__(256) void transpose_v64(const u16* __restrict__ V, u16* __restrict__ Vt) {
  __shared__ __align__(16) u16 tile[64][72];
  const int st = blockIdx.x, bh = blockIdx.y;
  const u16* src = V + ((size_t)bh * 2048 + st * 64) * 64;
  u16* dst = Vt + (size_t)bh * 64 * 2048 + st * 64;
  const int t = threadIdx.x;
  const int r = t >> 2, c0 = (t & 3) * 16;
#pragma unroll
  for (int j = 0; j < 2; ++j)
    *(u16x8*)&tile[r][c0 + j * 8] = *(const u16x8*)&src[(size_t)r * 64 + c0 + j * 8];
  __syncthreads();
  u16 tmp[16];
#pragma unroll
  for (int j = 0; j < 16; ++j) tmp[j] = tile[c0 + j][r];
#pragma unroll
  for (int j = 0; j < 2; ++j)
    *(u16x8*)&dst[(size_t)r * 2048 + c0 + j * 8] = *(const u16x8*)&tmp[j * 8];
}

// ---------------- Flash attention: r9 body (paired q-tiles + KV-parity, swapped QK^T) ----
__global__ __launch_bounds__(256) void attn_fwd_pair(const u16* __restrict__ Q, const u16* __restrict__ Kg,
                                                     const u16* __restrict__ Vt,
                                                     u16* __restrict__ accP, float* __restrict__ lP) {
  __shared__ __align__(16) u16 sK[2][64 * 64];
  __shared__ __align__(16) u16 sV[2][64 * 64];
  __shared__ __align__(16) u16 sP[4][16 * 64];

  const int tid = threadIdx.x;
  const int w = tid >> 6, lane = tid & 63;
  const int l15 = lane & 15, lg = lane >> 4;
  const int qiA = blockIdx.x;
  const int qiB = 31 - qiA;
  const int z = blockIdx.z;
  const int bh = blockIdx.y, b = bh >> 4, h = bh & 15, kvh = h >> 2;

  const u16* Qp = Q + (size_t)(b * 16 + h) * 2048 * 64;
  const u16* Kp = Kg + (size_t)(b * 4 + kvh) * 2048 * 64;
  const u16* Vp = Vt + (size_t)(b * 4 + kvh) * 64 * 2048;

  const int q0s[2] = {qiA * 64, qiB * 64};
  bf16x8 qa[2][2];
#pragma unroll
  for (int s = 0; s < 2; ++s) {
    const u16* qrow = Qp + (size_t)(q0s[s] + w * 16 + l15) * 64 + lg * 8;
    qa[s][0] = *(const bf16x8*)qrow;
    qa[s][1] = *(const bf16x8*)(qrow + 32);
  }

  f32x4 acc[2][4] = {};
  float l_s[2] = {0.f, 0.f};

  const int srw = tid >> 2;
  const int scb = (tid & 3) * 32;
  const int swzS = (srw & 7) << 4;
  const int st0 = srw * 128 + (scb ^ swzS);
  const int st1 = srw * 128 + ((scb + 16) ^ swzS);
  const u16* kgp = Kp + (size_t)srw * 64 + (tid & 3) * 16;
  const u16* vgp = Vp + (size_t)srw * 2048 + (tid & 3) * 16;

  const int swzF = (l15 & 7) << 4;
  const int fo0 = (lg * 16) ^ swzF;
  const int fo1 = (64 + lg * 16) ^ swzF;

  u16x8 kr0 = *(const u16x8*)(kgp + (size_t)z * 64 * 64), kr1 = *(const u16x8*)(kgp + (size_t)z * 64 * 64 + 8);
  u16x8 vr0 = *(const u16x8*)(vgp + z * 64),              vr1 = *(const u16x8*)(vgp + z * 64 + 8);
  *(u16x8*)((char*)sK[0] + st0) = kr0; *(u16x8*)((char*)sK[0] + st1) = kr1;
  *(u16x8*)((char*)sV[0] + st0) = vr0; *(u16x8*)((char*)sV[0] + st1) = vr1;
  __syncthreads();

  for (int t = z; t <= qiB; t += 2) {
    const int buf = (t >> 1) & 1;

    if (t + 2 <= qiB) {
      const u16* kg = kgp + (size_t)(t + 2) * 64 * 64;
      const u16* vg = vgp + (t + 2) * 64;
      kr0 = *(const u16x8*)kg; kr1 = *(const u16x8*)(kg + 8);
      vr0 = *(const u16x8*)vg; vr1 = *(const u16x8*)(vg + 8);
    }

    bf16x8 kf[4][2], vf[4][2];
#pragma unroll
    for (int ct = 0; ct < 4; ++ct) {
      const char* krow = (const char*)sK[buf] + (ct * 16 + l15) * 128;
      const char* vrow = (const char*)sV[buf] + (ct * 16 + l15) * 128;
      kf[ct][0] = *(const bf16x8*)(krow + fo0);
      kf[ct][1] = *(const bf16x8*)(krow + fo1);
      vf[ct][0] = *(const bf16x8*)(vrow + fo0);
      vf[ct][1] = *(const bf16x8*)(vrow + fo1);
    }

#pragma unroll
    for (int s = 0; s < 2; ++s) {
      if (s == 0 && t > qiA) continue;
      const int diag = s ? qiB : qiA;

      f32x4 st[4];
#pragma unroll
      for (int ct = 0; ct < 4; ++ct) {
        f32x4 s4 = {};
        s4 = __builtin_amdgcn_mfma_f32_16x16x32_bf16(kf[ct][0], qa[s][0], s4, 0, 0, 0);
        s4 = __builtin_amdgcn_mfma_f32_16x16x32_bf16(kf[ct][1], qa[s][1], s4, 0, 0, 0);
        st[ct] = s4;
      }

      if (t == diag) {
        const int ql = w * 16 + l15;
#pragma unroll
        for (int ct = 0; ct < 4; ++ct)
#pragma unroll
          for (int i = 0; i < 4; ++i)
            st[ct][i] = (ct * 16 + lg * 4 + i <= ql) ? st[ct][i] : -1e30f;
      }

      float ls = 0.f;
      const int swzP = (l15 & 7) << 4;
      char* prow = (char*)sP[w] + l15 * 128;
#pragma unroll
      for (int ct = 0; ct < 4; ++ct) {
        float p0 = exp2f(st[ct][0]), p1 = exp2f(st[ct][1]);
        float p2 = exp2f(st[ct][2]), p3 = exp2f(st[ct][3]);
        ls += (p0 + p1) + (p2 + p3);
        u32 lo = (u32)f2bfh(p0) | ((u32)f2bfh(p1) << 16);
        u32 hi = (u32)f2bfh(p2) | ((u32)f2bfh(p3) << 16);
        *(u32x2*)(prow + ((ct * 32 + lg * 8) ^ swzP)) = (u32x2){lo, hi};
      }
      l_s[s] += ls;

      bf16x8 pa0 = *(const bf16x8*)(prow + ((lg * 16) ^ swzP));
      bf16x8 pa1 = *(const bf16x8*)(prow + ((64 + lg * 16) ^ swzP));

#pragma unroll
      for (int n = 0; n < 4; ++n) {
        acc[s][n] = __builtin_amdgcn_mfma_f32_16x16x32_bf16(pa0, vf[n][0], acc[s][n], 0, 0, 0);
        acc[s][n] = __builtin_amdgcn_mfma_f32_16x16x32_bf16(pa1, vf[n][1], acc[s][n], 0, 0, 0);
      }
    }

    if (t + 2 <= qiB) {
      *(u16x8*)((char*)sK[buf ^ 1] + st0) = kr0; *(u16x8*)((char*)sK[buf ^ 1] + st1) = kr1;
      *(u16x8*)((char*)sV[buf ^ 1] + st0) = vr0; *(u16x8*)((char*)sV[buf ^ 1] + st1) = vr1;
    }
    __syncthreads();
  }

#pragma unroll
  for (int s = 0; s < 2; ++s) {
    float lv = l_s[s];
    lv += __shfl_xor(lv, 16);
    lv += __shfl_xor(lv, 32);
    if (lg == 0) {
      int qrow = q0s[s] + w * 16 + l15;
      lP[((size_t)z * 4096 + b * 2048 + qrow) * 16 + h] = lv;
    }
#pragma unroll
    for (int i = 0; i < 4; ++i) {
      int srowg = q0s[s] + w * 16 + lg * 4 + i;
      size_t rowbase = (size_t)z * 4096 + b * 2048 + srowg;
      u16* orow = accP + rowbase * 1024 + h * 64 + l15;
#pragma unroll
      for (int n = 0; n < 4; ++n) orow[n * 16] = f2bfh(acc[s][n][i]);
    }
  }
}

// ---------------- combine + gate: O = (a0+a1)/(l0+l1) * sigmoid(x[:12]@gw[h]) ----------
__global__ __launch_bounds__(256) void attn_combine(const u16* __restrict__ accP, const float* __restrict__ lP,
                                                    const float* __restrict__ x, const float* __restrict__ gw,
                                                    u16* __restrict__ attnh) {
  const size_t e = ((size_t)blockIdx.x * 256 + threadIdx.x) * 8;
  const int token = (int)(e >> 10);
  const int h = (int)((e >> 6) & 15);
  u16x8 a0 = *(const u16x8*)(accP + e);
  u16x8 a1 = *(const u16x8*)(accP + ((size_t)4096 << 10) + e);
  const size_t li = (size_t)token * 16 + h;
  float l = lP[li] + lP[(size_t)4096 * 16 + li];
  float gd = 0.f;
#pragma unroll
  for (int j = 0; j < 12; ++j) gd += x[(size_t)token * 1024 + j] * gw[h * 12 + j];
  float g = (1.0f / (1.0f + __expf(-gd))) / l;
  u16x8 o;
#pragma unroll
  for (int j = 0; j < 8; ++j) o[j] = f2bfh((bf2f(a0[j]) + bf2f(a1[j])) * g);
  *(u16x8*)(attnh + e) = o;
}

// ---------------- launch ----------------
extern "C" void kernel_launch(void* const* d_in, const int* in_sizes, int n_in,
                              void* d_out, int out_size, void* d_ws, size_t ws_size,
                              hipStream_t stream) {
  const float* x  = (const float*)d_in[0];
  const float* Wf = (const float*)d_in[1];
  const float* qw = (const float*)d_in[2];
  const float* kw = (const float*)d_in[3];
  const float* gw = (const float*)d_in[4];
  float* out = (float*)d_out;

  char* ws = (char*)d_ws;
  size_t off = 0;
  auto alloc = [&](size_t bytes) { void* p = ws + off; off += (bytes + 255) & ~(size_t)255; return p; };

  u16*    xb   = (u16*)alloc((size_t)4096 * 1024 * 2);
  u16*    wb   = (u16*)alloc((size_t)2560 * 1024 * 2);
  float2* tab  = (float2*)alloc((size_t)2048 * 32 * 8);
  u16*    Qb   = (u16*)alloc((size_t)2 * 16 * 2048 * 64 * 2);
  u16*    Kb   = (u16*)alloc((size_t)2 * 4 * 2048 * 64 * 2);
  u16*    Vb   = (u16*)alloc((size_t)2 * 4 * 2048 * 64 * 2);
  u16*    Vtb  = (u16*)alloc((size_t)2 * 4 * 2048 * 64 * 2);
  float*  lP   = (float*)alloc((size_t)2 * 4096 * 16 * 4);
  u16*    accP = (u16*)alloc((size_t)2 * 4096 * 1024 * 2);
  // attnh aliases xb (dead after gemm_qkv)
  u16* attnh = xb;

  cvt2_bf16<<<dim3(6656), dim3(256), 0, stream>>>(x, xb, 4096 * 1024 / 4, Wf, wb, 2560 * 1024 / 4);
  rope_tab_k<<<dim3(256), dim3(256), 0, stream>>>(tab);
  gemm_qkv<<<dim3(32, 12), dim3(256), 0, stream>>>(xb, wb, qw, kw, tab, Qb, Kb, Vb, 1024);
  transpose_v64<<<dim3(32, 8), dim3(256), 0, stream>>>(Vb, Vtb);
  attn_fwd_pair<<<dim3(16, 32, 2), dim3(256), 0, stream>>>(Qb, Kb, Vtb, accP, lP);
  attn_combine<<<dim3(2048), dim3(256), 0, stream>>>(accP, lP, x, gw, attnh);
  gemm_nt<<<dim3(32, 8), dim3(256), 0, stream>>>(attnh, wb + (size_t)1536 * 1024, out, 4096, 1024, 1024);
}

// Round 15
// 127.478 us; speedup vs baseline: 1.1694x; 1.0186x over previous
//
#include <hip/hip_runtime.h>
#include <math.h>

typedef unsigned short u16;
typedef unsigned int u32;
typedef __bf16 bf16x8 __attribute__((ext_vector_type(8)));
typedef float f32x4 __attribute__((ext_vector_type(4)));
typedef unsigned short u16x8 __attribute__((ext_vector_type(8)));
typedef unsigned int u32x2 __attribute__((ext_vector_type(2)));

static __device__ __forceinline__ u16 f2bf(float f) {
  unsigned int u = __builtin_bit_cast(unsigned int, f);
  u = (u + 0x7FFFu + ((u >> 16) & 1u)) >> 16;
  return (u16)u;
}
static __device__ __forceinline__ float bf2f(u16 u) {
  unsigned int x = ((unsigned int)u) << 16;
  return __builtin_bit_cast(float, x);
}
static __device__ __forceinline__ u16 f2bfh(float f) {
  __bf16 b = (__bf16)f;
  return __builtin_bit_cast(u16, b);
}
static __device__ __forceinline__ void gll16(const u16* g, u16* l) {
  __builtin_amdgcn_global_load_lds((const __attribute__((address_space(1))) u32*)g,
                                   (__attribute__((address_space(3))) u32*)l, 16, 0, 0);
}

#define QSCALE 0.18033688011112042f

// ---------------- fused f32 -> bf16 convert for two buffers ----------------
__global__ __launch_bounds__(256) void cvt2_bf16(const float* __restrict__ a, u16* __restrict__ da, int n4a,
                                                 const float* __restrict__ b, u16* __restrict__ db, int n4b) {
  int idx = blockIdx.x * 256 + threadIdx.x;
  const float* src; u16* dst; int i;
  if (idx < n4a) { src = a; dst = da; i = idx; }
  else { i = idx - n4a; if (i >= n4b) return; src = b; dst = db; }
  float4 v = ((const float4*)src)[i];
  ushort4 r;
  r.x = f2bf(v.x); r.y = f2bf(v.y); r.z = f2bf(v.z); r.w = f2bf(v.w);
  ((ushort4*)dst)[i] = r;
}

// ---------------- RoPE cos/sin table: tab[s][j] = (cos, sin), j = d>>1 ----------------
__global__ __launch_bounds__(256) void rope_tab_k(float2* __restrict__ tab) {
  int idx = blockIdx.x * 256 + threadIdx.x;   // 2048*32 entries
  int s = idx >> 5, j = idx & 31;
  float sn, cs;
  sincosf((float)s * expf(-(float)j * (9.21034037198f / 32.0f)), &sn, &cs);
  tab[idx] = make_float2(cs, sn);
}

// ---------------- bf16 NT GEMM, m97 structure (out-proj) ----------------
__global__ __launch_bounds__(256) void gemm_nt(const u16* __restrict__ A, const u16* __restrict__ B,
                                               float* __restrict__ C, int M, int N, int K) {
  __shared__ __align__(16) u16 sA[128 * 32];
  __shared__ __align__(16) u16 sB[128 * 32];
  const int tid = threadIdx.x;
  const int w = tid >> 6, lane = tid & 63, l15 = lane & 15;
  const int m0 = blockIdx.x * 128, n0 = blockIdx.y * 128;
  const int wm = (w >> 1) * 64, wn = (w & 1) * 64;

  f32x4 acc[4][4] = {};

  const int pb0 = w * 1024 + lane * 16;
  int srow[2], scol[2];
#pragma unroll
  for (int i = 0; i < 2; ++i) {
    int p = pb0 + i * 4096;
    int row = p >> 6, oo = p & 63;
    int ol = oo ^ (((row >> 1) & 3) << 4);
    srow[i] = row; scol[i] = ol >> 1;
  }
  int aoff[4], boff[4];
  const int kb = (lane >> 4) * 16;
#pragma unroll
  for (int m = 0; m < 4; ++m) {
    int r = wm + m * 16 + l15;
    aoff[m] = r * 64 + (kb ^ (((r >> 1) & 3) << 4));
  }
#pragma unroll
  for (int n = 0; n < 4; ++n) {
    int r = wn + n * 16 + l15;
    boff[n] = r * 64 + (kb ^ (((r >> 1) & 3) << 4));
  }

  for (int k0 = 0; k0 < K; k0 += 32) {
#pragma unroll
    for (int i = 0; i < 2; ++i) {
      int p = pb0 + i * 4096;
      gll16(A + (size_t)(m0 + srow[i]) * K + k0 + scol[i], (u16*)((char*)sA + p));
      gll16(B + (size_t)(n0 + srow[i]) * K + k0 + scol[i], (u16*)((char*)sB + p));
    }
    __syncthreads();
    bf16x8 af[4], bfr[4];
#pragma unroll
    for (int m = 0; m < 4; ++m) af[m] = *(const bf16x8*)((const char*)sA + aoff[m]);
#pragma unroll
    for (int n = 0; n < 4; ++n) bfr[n] = *(const bf16x8*)((const char*)sB + boff[n]);
#pragma unroll
    for (int m = 0; m < 4; ++m)
#pragma unroll
      for (int n = 0; n < 4; ++n)
        acc[m][n] = __builtin_amdgcn_mfma_f32_16x16x32_bf16(af[m], bfr[n], acc[m][n], 0, 0, 0);
    __syncthreads();
  }

#pragma unroll
  for (int m = 0; m < 4; ++m)
#pragma unroll
    for (int i = 0; i < 4; ++i) {
      int gr = m0 + wm + m * 16 + (lane >> 4) * 4 + i;
      float* crow = C + (size_t)gr * N + n0 + wn + l15;
#pragma unroll
      for (int n = 0; n < 4; ++n) crow[n * 16] = acc[m][n][i];
    }
}

// ---------------- QKV GEMM with fused RMSNorm+RoPE epilogue ----------------
__global__ __launch_bounds__(256) void gemm_qkv(const u16* __restrict__ A, const u16* __restrict__ B,
                                                const float* __restrict__ qw, const float* __restrict__ kw,
                                                const float2* __restrict__ tab,
                                                u16* __restrict__ Qo, u16* __restrict__ Ko,
                                                u16* __restrict__ Vo, int K) {
  __shared__ __align__(16) u16 sA[128 * 32];
  __shared__ __align__(16) u16 sB[128 * 32];
  const int tid = threadIdx.x;
  const int w = tid >> 6, lane = tid & 63, l15 = lane & 15, lg = lane >> 4;
  const int m0 = blockIdx.x * 128, n0 = blockIdx.y * 128;
  const int wm = (w >> 1) * 64, wn = (w & 1) * 64;

  f32x4 acc[4][4] = {};

  const int pb0 = w * 1024 + lane * 16;
  int srow[2], scol[2];
#pragma unroll
  for (int i = 0; i < 2; ++i) {
    int p = pb0 + i * 4096;
    int row = p >> 6, oo = p & 63;
    int ol = oo ^ (((row >> 1) & 3) << 4);
    srow[i] = row; scol[i] = ol >> 1;
  }
  int aoff[4], boff[4];
  const int kb = lg * 16;
#pragma unroll
  for (int m = 0; m < 4; ++m) {
    int r = wm + m * 16 + l15;
    aoff[m] = r * 64 + (kb ^ (((r >> 1) & 3) << 4));
  }
#pragma unroll
  for (int n = 0; n < 4; ++n) {
    int r = wn + n * 16 + l15;
    boff[n] = r * 64 + (kb ^ (((r >> 1) & 3) << 4));
  }

  for (int k0 = 0; k0 < K; k0 += 32) {
#pragma unroll
    for (int i = 0; i < 2; ++i) {
      int p = pb0 + i * 4096;
      gll16(A + (size_t)(m0 + srow[i]) * K + k0 + scol[i], (u16*)((char*)sA + p));
      gll16(B + (size_t)(n0 + srow[i]) * K + k0 + scol[i], (u16*)((char*)sB + p));
    }
    __syncthreads();
    bf16x8 af[4], bfr[4];
#pragma unroll
    for (int m = 0; m < 4; ++m) af[m] = *(const bf16x8*)((const char*)sA + aoff[m]);
#pragma unroll
    for (int n = 0; n < 4; ++n) bfr[n] = *(const bf16x8*)((const char*)sB + boff[n]);
#pragma unroll
    for (int m = 0; m < 4; ++m)
#pragma unroll
      for (int n = 0; n < 4; ++n)
        acc[m][n] = __builtin_amdgcn_mfma_f32_16x16x32_bf16(af[m], bfr[n], acc[m][n], 0, 0, 0);
    __syncthreads();
  }

  const int he = (n0 + wn) >> 6;   // wave-uniform head index 0..23
  if (he < 20) {
    const float* wnorm = (he < 16) ? qw : kw;
    const float oscale = (he < 16) ? QSCALE : 1.0f;
    float wv[4];
#pragma unroll
    for (int n = 0; n < 4; ++n) wv[n] = wnorm[n * 16 + l15];
    float2 tj[4];
#pragma unroll
    for (int m = 0; m < 4; ++m)
#pragma unroll
      for (int i = 0; i < 4; ++i) {
        const int gr = m0 + wm + m * 16 + lg * 4 + i;
        const int s = gr & 2047, bb = gr >> 11;
        float ss = 0.f;
#pragma unroll
        for (int n = 0; n < 4; ++n) ss += acc[m][n][i] * acc[m][n][i];
        ss += __shfl_xor(ss, 8); ss += __shfl_xor(ss, 4);
        ss += __shfl_xor(ss, 2); ss += __shfl_xor(ss, 1);
        const float r = rsqrtf(ss * (1.0f / 64.0f) + 1.1920929e-7f);
#pragma unroll
        for (int n = 0; n < 4; ++n) tj[n] = tab[s * 32 + n * 8 + (l15 >> 1)];
        u16* orow = (he < 16)
          ? Qo + ((size_t)(bb * 16 + he) * 2048 + s) * 64 + l15
          : Ko + ((size_t)(bb * 4 + (he - 16)) * 2048 + s) * 64 + l15;
#pragma unroll
        for (int n = 0; n < 4; ++n) {
          float xn = acc[m][n][i] * r * wv[n];
          float p = __shfl_xor(xn, 1);
          float outv = ((l15 & 1) == 0) ? (xn * tj[n].x - p * tj[n].y)
                                        : (xn * tj[n].x + p * tj[n].y);
          orow[n * 16] = f2bf(outv * oscale);
        }
      }
  } else {
#pragma unroll
    for (int m = 0; m < 4; ++m)
#pragma unroll
      for (int i = 0; i < 4; ++i) {
        const int gr = m0 + wm + m * 16 + lg * 4 + i;
        const int s = gr & 2047, bb = gr >> 11;
        u16* orow = Vo + ((size_t)(bb * 4 + (he - 20)) * 2048 + s) * 64 + l15;
#pragma unroll
        for (int n = 0; n < 4; ++n) orow[n * 16] = f2bf(acc[m][n][i]);
      }
  }
}

// ---------------- V transpose: [bh][s][d] -> [bh][d][s] ----------------
__global__ __launch_bounds__(256) void transpose_v64(const u16* __restrict__ V, u16* __restrict__ Vt) {
  __shared__ __align__(16) u16 tile[64][72];
  const int st = blockIdx.x, bh = blockIdx.y;
  const u16* src = V + ((size_t)bh * 2048 + st * 64) * 64;
  u16* dst = Vt + (size_t)bh * 64 * 2048 + st * 64;
  const int t = threadIdx.x;
  const int r = t >> 2, c0 = (t & 3) * 16;
#pragma unroll
  for (int j = 0; j < 2; ++j)
    *(u16x8*)&tile[r][c0 + j * 8] = *(const u16x8*)&src[(size_t)r * 64 + c0 + j * 8];
  __syncthreads();
  u16 tmp[16];
#pragma unroll
  for (int j = 0; j < 16; ++j) tmp[j] = tile[c0 + j][r];
#pragma unroll
  for (int j = 0; j < 2; ++j)
    *(u16x8*)&dst[(size_t)r * 2048 + c0 + j * 8] = *(const u16x8*)&tmp[j * 8];
}

// ---------------- Flash attention: r13 arithmetic, single-buffer reg-staged K/V ------
// grid (16, B*H, 2). LDS = 24576 B (sK 8K + sV 8K + sP 8K) -> 4 blocks/CU co-resident
// (grid = exactly 4/CU). Schedule (r10-proven shape): barrier A (safe to overwrite) ->
// ds_write prefetched regs -> barrier B (visible) -> issue next tile's global loads
// (latency hides under compute) -> fragments + both softmax/PV streams.
__global__ __launch_bounds__(256) void attn_fwd_pair(const u16* __restrict__ Q, const u16* __restrict__ Kg,
                                                     const u16* __restrict__ Vt,
                                                     u16* __restrict__ accP, float* __restrict__ lP) {
  __shared__ __align__(16) u16 sK[64 * 64];
  __shared__ __align__(16) u16 sV[64 * 64];
  __shared__ __align__(16) u16 sP[4][16 * 64];

  const int tid = threadIdx.x;
  const int w = tid >> 6, lane = tid & 63;
  const int l15 = lane & 15, lg = lane >> 4;
  const int qiA = blockIdx.x;
  const int qiB = 31 - qiA;
  const int z = blockIdx.z;
  const int bh = blockIdx.y, b = bh >> 4, h = bh & 15, kvh = h >> 2;

  const u16* Qp = Q + (size_t)(b * 16 + h) * 2048 * 64;
  const u16* Kp = Kg + (size_t)(b * 4 + kvh) * 2048 * 64;
  const u16* Vp = Vt + (size_t)(b * 4 + kvh) * 64 * 2048;

  const int q0s[2] = {qiA * 64, qiB * 64};
  bf16x8 qa[2][2];
#pragma unroll
  for (int s = 0; s < 2; ++s) {
    const u16* qrow = Qp + (size_t)(q0s[s] + w * 16 + l15) * 64 + lg * 8;
    qa[s][0] = *(const bf16x8*)qrow;
    qa[s][1] = *(const bf16x8*)(qrow + 32);
  }

  f32x4 acc[2][4] = {};
  float l_s[2] = {0.f, 0.f};

  // reg-staging addresses: global linear; LDS swizzled (T2: byte ^= (row&7)<<4, both sides)
  const int srw = tid >> 2;
  const int scb = (tid & 3) * 32;
  const int swzS = (srw & 7) << 4;
  const int st0 = srw * 128 + (scb ^ swzS);
  const int st1 = srw * 128 + ((scb + 16) ^ swzS);
  const u16* kgp = Kp + (size_t)srw * 64 + (tid & 3) * 16;
  const u16* vgp = Vp + (size_t)srw * 2048 + (tid & 3) * 16;

  const int swzF = (l15 & 7) << 4;
  const int fo0 = (lg * 16) ^ swzF;
  const int fo1 = (64 + lg * 16) ^ swzF;

  // prologue: load tile z into regs
  u16x8 kr0 = *(const u16x8*)(kgp + (size_t)z * 64 * 64), kr1 = *(const u16x8*)(kgp + (size_t)z * 64 * 64 + 8);
  u16x8 vr0 = *(const u16x8*)(vgp + z * 64),              vr1 = *(const u16x8*)(vgp + z * 64 + 8);

  for (int t = z; t <= qiB; t += 2) {
    __syncthreads();   // all waves done reading the previous tile (trivial on iter 0)
    *(u16x8*)((char*)sK + st0) = kr0; *(u16x8*)((char*)sK + st1) = kr1;
    *(u16x8*)((char*)sV + st0) = vr0; *(u16x8*)((char*)sV + st1) = vr1;
    __syncthreads();   // staged tile visible

    // T14: issue tile t+2's global loads now; consumed at next iteration's ds_write.
    if (t + 2 <= qiB) {
      const u16* kg = kgp + (size_t)(t + 2) * 64 * 64;
      const u16* vg = vgp + (t + 2) * 64;
      kr0 = *(const u16x8*)kg; kr1 = *(const u16x8*)(kg + 8);
      vr0 = *(const u16x8*)vg; vr1 = *(const u16x8*)(vg + 8);
    }

    bf16x8 kf[4][2], vf[4][2];
#pragma unroll
    for (int ct = 0; ct < 4; ++ct) {
      const char* krow = (const char*)sK + (ct * 16 + l15) * 128;
      const char* vrow = (const char*)sV + (ct * 16 + l15) * 128;
      kf[ct][0] = *(const bf16x8*)(krow + fo0);
      kf[ct][1] = *(const bf16x8*)(krow + fo1);
      vf[ct][0] = *(const bf16x8*)(vrow + fo0);
      vf[ct][1] = *(const bf16x8*)(vrow + fo1);
    }

#pragma unroll
    for (int s = 0; s < 2; ++s) {
      if (s == 0 && t > qiA) continue;
      const int diag = s ? qiB : qiA;

      f32x4 st[4];
#pragma unroll
      for (int ct = 0; ct < 4; ++ct) {
        f32x4 s4 = {};
        s4 = __builtin_amdgcn_mfma_f32_16x16x32_bf16(kf[ct][0], qa[s][0], s4, 0, 0, 0);
        s4 = __builtin_amdgcn_mfma_f32_16x16x32_bf16(kf[ct][1], qa[s][1], s4, 0, 0, 0);
        st[ct] = s4;
      }

      if (t == diag) {
        const int ql = w * 16 + l15;
#pragma unroll
        for (int ct = 0; ct < 4; ++ct)
#pragma unroll
          for (int i = 0; i < 4; ++i)
            st[ct][i] = (ct * 16 + lg * 4 + i <= ql) ? st[ct][i] : -1e30f;
      }

      float ls = 0.f;
      const int swzP = (l15 & 7) << 4;
      char* prow = (char*)sP[w] + l15 * 128;
#pragma unroll
      for (int ct = 0; ct < 4; ++ct) {
        float p0 = exp2f(st[ct][0]), p1 = exp2f(st[ct][1]);
        float p2 = exp2f(st[ct][2]), p3 = exp2f(st[ct][3]);
        ls += (p0 + p1) + (p2 + p3);
        u32 lo = (u32)f2bfh(p0) | ((u32)f2bfh(p1) << 16);
        u32 hi = (u32)f2bfh(p2) | ((u32)f2bfh(p3) << 16);
        *(u32x2*)(prow + ((ct * 32 + lg * 8) ^ swzP)) = (u32x2){lo, hi};
      }
      l_s[s] += ls;

      bf16x8 pa0 = *(const bf16x8*)(prow + ((lg * 16) ^ swzP));
      bf16x8 pa1 = *(const bf16x8*)(prow + ((64 + lg * 16) ^ swzP));

#pragma unroll
      for (int n = 0; n < 4; ++n) {
        acc[s][n] = __builtin_amdgcn_mfma_f32_16x16x32_bf16(pa0, vf[n][0], acc[s][n], 0, 0, 0);
        acc[s][n] = __builtin_amdgcn_mfma_f32_16x16x32_bf16(pa1, vf[n][1], acc[s][n], 0, 0, 0);
      }
    }
  }

#pragma unroll
  for (int s = 0; s < 2; ++s) {
    float lv = l_s[s];
    lv += __shfl_xor(lv, 16);
    lv += __shfl_xor(lv, 32);
    if (lg == 0) {
      int qrow = q0s[s] + w * 16 + l15;
      lP[((size_t)z * 4096 + b * 2048 + qrow) * 16 + h] = lv;
    }
#pragma unroll
    for (int i = 0; i < 4; ++i) {
      int srowg = q0s[s] + w * 16 + lg * 4 + i;
      size_t rowbase = (size_t)z * 4096 + b * 2048 + srowg;
      u16* orow = accP + rowbase * 1024 + h * 64 + l15;
#pragma unroll
      for (int n = 0; n < 4; ++n) orow[n * 16] = f2bfh(acc[s][n][i]);
    }
  }
}

// ---------------- combine + gate: O = (a0+a1)/(l0+l1) * sigmoid(x[:12]@gw[h]) ----------
__global__ __launch_bounds__(256) void attn_combine(const u16* __restrict__ accP, const float* __restrict__ lP,
                                                    const float* __restrict__ x, const float* __restrict__ gw,
                                                    u16* __restrict__ attnh) {
  const size_t e = ((size_t)blockIdx.x * 256 + threadIdx.x) * 8;
  const int token = (int)(e >> 10);
  const int h = (int)((e >> 6) & 15);
  u16x8 a0 = *(const u16x8*)(accP + e);
  u16x8 a1 = *(const u16x8*)(accP + ((size_t)4096 << 10) + e);
  const size_t li = (size_t)token * 16 + h;
  float l = lP[li] + lP[(size_t)4096 * 16 + li];
  float gd = 0.f;
#pragma unroll
  for (int j = 0; j < 12; ++j) gd += x[(size_t)token * 1024 + j] * gw[h * 12 + j];
  float g = (1.0f / (1.0f + __expf(-gd))) / l;
  u16x8 o;
#pragma unroll
  for (int j = 0; j < 8; ++j) o[j] = f2bfh((bf2f(a0[j]) + bf2f(a1[j])) * g);
  *(u16x8*)(attnh + e) = o;
}

// ---------------- launch ----------------
extern "C" void kernel_launch(void* const* d_in, const int* in_sizes, int n_in,
                              void* d_out, int out_size, void* d_ws, size_t ws_size,
                              hipStream_t stream) {
  const float* x  = (const float*)d_in[0];
  const float* Wf = (const float*)d_in[1];
  const float* qw = (const float*)d_in[2];
  const float* kw = (const float*)d_in[3];
  const float* gw = (const float*)d_in[4];
  float* out = (float*)d_out;

  char* ws = (char*)d_ws;
  size_t off = 0;
  auto alloc = [&](size_t bytes) { void* p = ws + off; off += (bytes + 255) & ~(size_t)255; return p; };

  u16*    xb   = (u16*)alloc((size_t)4096 * 1024 * 2);
  u16*    wb   = (u16*)alloc((size_t)2560 * 1024 * 2);
  float2* tab  = (float2*)alloc((size_t)2048 * 32 * 8);
  u16*    Qb   = (u16*)alloc((size_t)2 * 16 * 2048 * 64 * 2);
  u16*    Kb   = (u16*)alloc((size_t)2 * 4 * 2048 * 64 * 2);
  u16*    Vb   = (u16*)alloc((size_t)2 * 4 * 2048 * 64 * 2);
  u16*    Vtb  = (u16*)alloc((size_t)2 * 4 * 2048 * 64 * 2);
  float*  lP   = (float*)alloc((size_t)2 * 4096 * 16 * 4);
  u16*    accP = (u16*)alloc((size_t)2 * 4096 * 1024 * 2);
  // attnh aliases xb (dead after gemm_qkv)
  u16* attnh = xb;

  cvt2_bf16<<<dim3(6656), dim3(256), 0, stream>>>(x, xb, 4096 * 1024 / 4, Wf, wb, 2560 * 1024 / 4);
  rope_tab_k<<<dim3(256), dim3(256), 0, stream>>>(tab);
  gemm_qkv<<<dim3(32, 12), dim3(256), 0, stream>>>(xb, wb, qw, kw, tab, Qb, Kb, Vb, 1024);
  transpose_v64<<<dim3(32, 8), dim3(256), 0, stream>>>(Vb, Vtb);
  attn_fwd_pair<<<dim3(16, 32, 2), dim3(256), 0, stream>>>(Qb, Kb, Vtb, accP, lP);
  attn_combine<<<dim3(2048), dim3(256), 0, stream>>>(accP, lP, x, gw, attnh);
  gemm_nt<<<dim3(32, 8), dim3(256), 0, stream>>>(attnh, wb + (size_t)1536 * 1024, out, 4096, 1024, 1024);
}

// Round 16
// 115.800 us; speedup vs baseline: 1.2874x; 1.1009x over previous
//
#include <hip/hip_runtime.h>
#include <math.h>

typedef unsigned short u16;
typedef unsigned int u32;
typedef __bf16 bf16x8 __attribute__((ext_vector_type(8)));
typedef float f32x4 __attribute__((ext_vector_type(4)));
typedef unsigned short u16x8 __attribute__((ext_vector_type(8)));
typedef unsigned int u32x2 __attribute__((ext_vector_type(2)));

static __device__ __forceinline__ u16 f2bf(float f) {
  unsigned int u = __builtin_bit_cast(unsigned int, f);
  u = (u + 0x7FFFu + ((u >> 16) & 1u)) >> 16;
  return (u16)u;
}
static __device__ __forceinline__ float bf2f(u16 u) {
  unsigned int x = ((unsigned int)u) << 16;
  return __builtin_bit_cast(float, x);
}
static __device__ __forceinline__ u16 f2bfh(float f) {
  __bf16 b = (__bf16)f;
  return __builtin_bit_cast(u16, b);
}
static __device__ __forceinline__ void gll16(const u16* g, u16* l) {
  __builtin_amdgcn_global_load_lds((const __attribute__((address_space(1))) u32*)g,
                                   (__attribute__((address_space(3))) u32*)l, 16, 0, 0);
}

#define QSCALE 0.18033688011112042f

// ---------------- fused f32 -> bf16 convert for two buffers ----------------
__global__ __launch_bounds__(256) void cvt2_bf16(const float* __restrict__ a, u16* __restrict__ da, int n4a,
                                                 const float* __restrict__ b, u16* __restrict__ db, int n4b) {
  int idx = blockIdx.x * 256 + threadIdx.x;
  const float* src; u16* dst; int i;
  if (idx < n4a) { src = a; dst = da; i = idx; }
  else { i = idx - n4a; if (i >= n4b) return; src = b; dst = db; }
  float4 v = ((const float4*)src)[i];
  ushort4 r;
  r.x = f2bf(v.x); r.y = f2bf(v.y); r.z = f2bf(v.z); r.w = f2bf(v.w);
  ((ushort4*)dst)[i] = r;
}

// ---------------- RoPE cos/sin table: tab[s][j] = (cos, sin), j = d>>1 ----------------
__global__ __launch_bounds__(256) void rope_tab_k(float2* __restrict__ tab) {
  int idx = blockIdx.x * 256 + threadIdx.x;   // 2048*32 entries
  int s = idx >> 5, j = idx & 31;
  float sn, cs;
  sincosf((float)s * expf(-(float)j * (9.21034037198f / 32.0f)), &sn, &cs);
  tab[idx] = make_float2(cs, sn);
}

// ---------------- bf16 NT GEMM, 64x128 tile (out-proj): gll16 staging ----------------
// 256 threads, 4 waves; wave tile 32(m) x 64(n). Grid (M/64, N/128) for residency.
__global__ __launch_bounds__(256) void gemm_nt(const u16* __restrict__ A, const u16* __restrict__ B,
                                               float* __restrict__ C, int M, int N, int K) {
  __shared__ __align__(16) u16 sA[64 * 32];
  __shared__ __align__(16) u16 sB[128 * 32];
  const int tid = threadIdx.x;
  const int w = tid >> 6, lane = tid & 63, l15 = lane & 15;
  const int m0 = blockIdx.x * 64, n0 = blockIdx.y * 128;
  const int wm = (w >> 1) * 32, wn = (w & 1) * 64;

  f32x4 acc[2][4] = {};

  // staging: sA one 4096B chunk (p = tid*16), sB two (p = i*4096 + tid*16); src pre-swizzled
  int sArow, sAcol;
  {
    int p = tid * 16;
    int row = p >> 6, oo = p & 63;
    int ol = oo ^ (((row >> 1) & 3) << 4);
    sArow = row; sAcol = ol >> 1;
  }
  int sBrow[2], sBcol[2];
#pragma unroll
  for (int i = 0; i < 2; ++i) {
    int p = i * 4096 + tid * 16;
    int row = p >> 6, oo = p & 63;
    int ol = oo ^ (((row >> 1) & 3) << 4);
    sBrow[i] = row; sBcol[i] = ol >> 1;
  }
  int aoff[2], boff[4];
  const int kb = (lane >> 4) * 16;
#pragma unroll
  for (int m = 0; m < 2; ++m) {
    int r = wm + m * 16 + l15;
    aoff[m] = r * 64 + (kb ^ (((r >> 1) & 3) << 4));
  }
#pragma unroll
  for (int n = 0; n < 4; ++n) {
    int r = wn + n * 16 + l15;
    boff[n] = r * 64 + (kb ^ (((r >> 1) & 3) << 4));
  }

  for (int k0 = 0; k0 < K; k0 += 32) {
    gll16(A + (size_t)(m0 + sArow) * K + k0 + sAcol, (u16*)((char*)sA + tid * 16));
#pragma unroll
    for (int i = 0; i < 2; ++i)
      gll16(B + (size_t)(n0 + sBrow[i]) * K + k0 + sBcol[i], (u16*)((char*)sB + i * 4096 + tid * 16));
    __syncthreads();
    bf16x8 af[2], bfr[4];
#pragma unroll
    for (int m = 0; m < 2; ++m) af[m] = *(const bf16x8*)((const char*)sA + aoff[m]);
#pragma unroll
    for (int n = 0; n < 4; ++n) bfr[n] = *(const bf16x8*)((const char*)sB + boff[n]);
#pragma unroll
    for (int m = 0; m < 2; ++m)
#pragma unroll
      for (int n = 0; n < 4; ++n)
        acc[m][n] = __builtin_amdgcn_mfma_f32_16x16x32_bf16(af[m], bfr[n], acc[m][n], 0, 0, 0);
    __syncthreads();
  }

#pragma unroll
  for (int m = 0; m < 2; ++m)
#pragma unroll
    for (int i = 0; i < 4; ++i) {
      int gr = m0 + wm + m * 16 + (lane >> 4) * 4 + i;
      float* crow = C + (size_t)gr * N + n0 + wn + l15;
#pragma unroll
      for (int n = 0; n < 4; ++n) crow[n * 16] = acc[m][n][i];
    }
}

// ---------------- QKV GEMM (64x128 tile) with fused RMSNorm+RoPE epilogue ----------------
// Wave tile 32 x 64: one wave spans exactly one head (wn in {0,64}); he = (n0+wn)>>6.
__global__ __launch_bounds__(256) void gemm_qkv(const u16* __restrict__ A, const u16* __restrict__ B,
                                                const float* __restrict__ qw, const float* __restrict__ kw,
                                                const float2* __restrict__ tab,
                                                u16* __restrict__ Qo, u16* __restrict__ Ko,
                                                u16* __restrict__ Vo, int K) {
  __shared__ __align__(16) u16 sA[64 * 32];
  __shared__ __align__(16) u16 sB[128 * 32];
  const int tid = threadIdx.x;
  const int w = tid >> 6, lane = tid & 63, l15 = lane & 15, lg = lane >> 4;
  const int m0 = blockIdx.x * 64, n0 = blockIdx.y * 128;
  const int wm = (w >> 1) * 32, wn = (w & 1) * 64;

  f32x4 acc[2][4] = {};

  int sArow, sAcol;
  {
    int p = tid * 16;
    int row = p >> 6, oo = p & 63;
    int ol = oo ^ (((row >> 1) & 3) << 4);
    sArow = row; sAcol = ol >> 1;
  }
  int sBrow[2], sBcol[2];
#pragma unroll
  for (int i = 0; i < 2; ++i) {
    int p = i * 4096 + tid * 16;
    int row = p >> 6, oo = p & 63;
    int ol = oo ^ (((row >> 1) & 3) << 4);
    sBrow[i] = row; sBcol[i] = ol >> 1;
  }
  int aoff[2], boff[4];
  const int kb = lg * 16;
#pragma unroll
  for (int m = 0; m < 2; ++m) {
    int r = wm + m * 16 + l15;
    aoff[m] = r * 64 + (kb ^ (((r >> 1) & 3) << 4));
  }
#pragma unroll
  for (int n = 0; n < 4; ++n) {
    int r = wn + n * 16 + l15;
    boff[n] = r * 64 + (kb ^ (((r >> 1) & 3) << 4));
  }

  for (int k0 = 0; k0 < K; k0 += 32) {
    gll16(A + (size_t)(m0 + sArow) * K + k0 + sAcol, (u16*)((char*)sA + tid * 16));
#pragma unroll
    for (int i = 0; i < 2; ++i)
      gll16(B + (size_t)(n0 + sBrow[i]) * K + k0 + sBcol[i], (u16*)((char*)sB + i * 4096 + tid * 16));
    __syncthreads();
    bf16x8 af[2], bfr[4];
#pragma unroll
    for (int m = 0; m < 2; ++m) af[m] = *(const bf16x8*)((const char*)sA + aoff[m]);
#pragma unroll
    for (int n = 0; n < 4; ++n) bfr[n] = *(const bf16x8*)((const char*)sB + boff[n]);
#pragma unroll
    for (int m = 0; m < 2; ++m)
#pragma unroll
      for (int n = 0; n < 4; ++n)
        acc[m][n] = __builtin_amdgcn_mfma_f32_16x16x32_bf16(af[m], bfr[n], acc[m][n], 0, 0, 0);
    __syncthreads();
  }

  const int he = (n0 + wn) >> 6;   // wave-uniform head index 0..23
  if (he < 20) {
    const float* wnorm = (he < 16) ? qw : kw;
    const float oscale = (he < 16) ? QSCALE : 1.0f;
    float wv[4];
#pragma unroll
    for (int n = 0; n < 4; ++n) wv[n] = wnorm[n * 16 + l15];
    float2 tj[4];
#pragma unroll
    for (int m = 0; m < 2; ++m)
#pragma unroll
      for (int i = 0; i < 4; ++i) {
        const int gr = m0 + wm + m * 16 + lg * 4 + i;
        const int s = gr & 2047, bb = gr >> 11;
        float ss = 0.f;
#pragma unroll
        for (int n = 0; n < 4; ++n) ss += acc[m][n][i] * acc[m][n][i];
        ss += __shfl_xor(ss, 8); ss += __shfl_xor(ss, 4);
        ss += __shfl_xor(ss, 2); ss += __shfl_xor(ss, 1);
        const float r = rsqrtf(ss * (1.0f / 64.0f) + 1.1920929e-7f);
#pragma unroll
        for (int n = 0; n < 4; ++n) tj[n] = tab[s * 32 + n * 8 + (l15 >> 1)];
        u16* orow = (he < 16)
          ? Qo + ((size_t)(bb * 16 + he) * 2048 + s) * 64 + l15
          : Ko + ((size_t)(bb * 4 + (he - 16)) * 2048 + s) * 64 + l15;
#pragma unroll
        for (int n = 0; n < 4; ++n) {
          float xn = acc[m][n][i] * r * wv[n];
          float p = __shfl_xor(xn, 1);
          float outv = ((l15 & 1) == 0) ? (xn * tj[n].x - p * tj[n].y)
                                        : (xn * tj[n].x + p * tj[n].y);
          orow[n * 16] = f2bf(outv * oscale);
        }
      }
  } else {
#pragma unroll
    for (int m = 0; m < 2; ++m)
#pragma unroll
      for (int i = 0; i < 4; ++i) {
        const int gr = m0 + wm + m * 16 + lg * 4 + i;
        const int s = gr & 2047, bb = gr >> 11;
        u16* orow = Vo + ((size_t)(bb * 4 + (he - 20)) * 2048 + s) * 64 + l15;
#pragma unroll
        for (int n = 0; n < 4; ++n) orow[n * 16] = f2bf(acc[m][n][i]);
      }
  }
}

// ---------------- V transpose: [bh][s][d] -> [bh][d][s] ----------------
__global__ __launch_bounds__(256) void transpose_v64(const u16* __restrict__ V, u16* __restrict__ Vt) {
  __shared__ __align__(16) u16 tile[64][72];
  const int st = blockIdx.x, bh = blockIdx.y;
  const u16* src = V + ((size_t)bh * 2048 + st * 64) * 64;
  u16* dst = Vt + (size_t)bh * 64 * 2048 + st * 64;
  const int t = threadIdx.x;
  const int r = t >> 2, c0 = (t & 3) * 16;
#pragma unroll
  for (int j = 0; j < 2; ++j)
    *(u16x8*)&tile[r][c0 + j * 8] = *(const u16x8*)&src[(size_t)r * 64 + c0 + j * 8];
  __syncthreads();
  u16 tmp[16];
#pragma unroll
  for (int j = 0; j < 16; ++j) tmp[j] = tile[c0 + j][r];
#pragma unroll
  for (int j = 0; j < 2; ++j)
    *(u16x8*)&dst[(size_t)r * 2048 + c0 + j * 8] = *(const u16x8*)&tmp[j * 8];
}

// ---------------- Flash attention: r15 body (paired q-tiles + KV-parity, 24.5 KB LDS) ----
__global__ __launch_bounds__(256) void attn_fwd_pair(const u16* __restrict__ Q, const u16* __restrict__ Kg,
                                                     const u16* __restrict__ Vt,
                                                     u16* __restrict__ accP, float* __restrict__ lP) {
  __shared__ __align__(16) u16 sK[64 * 64];
  __shared__ __align__(16) u16 sV[64 * 64];
  __shared__ __align__(16) u16 sP[4][16 * 64];

  const int tid = threadIdx.x;
  const int w = tid >> 6, lane = tid & 63;
  const int l15 = lane & 15, lg = lane >> 4;
  const int qiA = blockIdx.x;
  const int qiB = 31 - qiA;
  const int z = blockIdx.z;
  const int bh = blockIdx.y, b = bh >> 4, h = bh & 15, kvh = h >> 2;

  const u16* Qp = Q + (size_t)(b * 16 + h) * 2048 * 64;
  const u16* Kp = Kg + (size_t)(b * 4 + kvh) * 2048 * 64;
  const u16* Vp = Vt + (size_t)(b * 4 + kvh) * 64 * 2048;

  const int q0s[2] = {qiA * 64, qiB * 64};
  bf16x8 qa[2][2];
#pragma unroll
  for (int s = 0; s < 2; ++s) {
    const u16* qrow = Qp + (size_t)(q0s[s] + w * 16 + l15) * 64 + lg * 8;
    qa[s][0] = *(const bf16x8*)qrow;
    qa[s][1] = *(const bf16x8*)(qrow + 32);
  }

  f32x4 acc[2][4] = {};
  float l_s[2] = {0.f, 0.f};

  const int srw = tid >> 2;
  const int scb = (tid & 3) * 32;
  const int swzS = (srw & 7) << 4;
  const int st0 = srw * 128 + (scb ^ swzS);
  const int st1 = srw * 128 + ((scb + 16) ^ swzS);
  const u16* kgp = Kp + (size_t)srw * 64 + (tid & 3) * 16;
  const u16* vgp = Vp + (size_t)srw * 2048 + (tid & 3) * 16;

  const int swzF = (l15 & 7) << 4;
  const int fo0 = (lg * 16) ^ swzF;
  const int fo1 = (64 + lg * 16) ^ swzF;

  u16x8 kr0 = *(const u16x8*)(kgp + (size_t)z * 64 * 64), kr1 = *(const u16x8*)(kgp + (size_t)z * 64 * 64 + 8);
  u16x8 vr0 = *(const u16x8*)(vgp + z * 64),              vr1 = *(const u16x8*)(vgp + z * 64 + 8);

  for (int t = z; t <= qiB; t += 2) {
    __syncthreads();
    *(u16x8*)((char*)sK + st0) = kr0; *(u16x8*)((char*)sK + st1) = kr1;
    *(u16x8*)((char*)sV + st0) = vr0; *(u16x8*)((char*)sV + st1) = vr1;
    __syncthreads();

    if (t + 2 <= qiB) {
      const u16* kg = kgp + (size_t)(t + 2) * 64 * 64;
      const u16* vg = vgp + (t + 2) * 64;
      kr0 = *(const u16x8*)kg; kr1 = *(const u16x8*)(kg + 8);
      vr0 = *(const u16x8*)vg; vr1 = *(const u16x8*)(vg + 8);
    }

    bf16x8 kf[4][2], vf[4][2];
#pragma unroll
    for (int ct = 0; ct < 4; ++ct) {
      const char* krow = (const char*)sK + (ct * 16 + l15) * 128;
      const char* vrow = (const char*)sV + (ct * 16 + l15) * 128;
      kf[ct][0] = *(const bf16x8*)(krow + fo0);
      kf[ct][1] = *(const bf16x8*)(krow + fo1);
      vf[ct][0] = *(const bf16x8*)(vrow + fo0);
      vf[ct][1] = *(const bf16x8*)(vrow + fo1);
    }

#pragma unroll
    for (int s = 0; s < 2; ++s) {
      if (s == 0 && t > qiA) continue;
      const int diag = s ? qiB : qiA;

      f32x4 st[4];
#pragma unroll
      for (int ct = 0; ct < 4; ++ct) {
        f32x4 s4 = {};
        s4 = __builtin_amdgcn_mfma_f32_16x16x32_bf16(kf[ct][0], qa[s][0], s4, 0, 0, 0);
        s4 = __builtin_amdgcn_mfma_f32_16x16x32_bf16(kf[ct][1], qa[s][1], s4, 0, 0, 0);
        st[ct] = s4;
      }

      if (t == diag) {
        const int ql = w * 16 + l15;
#pragma unroll
        for (int ct = 0; ct < 4; ++ct)
#pragma unroll
          for (int i = 0; i < 4; ++i)
            st[ct][i] = (ct * 16 + lg * 4 + i <= ql) ? st[ct][i] : -1e30f;
      }

      float ls = 0.f;
      const int swzP = (l15 & 7) << 4;
      char* prow = (char*)sP[w] + l15 * 128;
#pragma unroll
      for (int ct = 0; ct < 4; ++ct) {
        float p0 = exp2f(st[ct][0]), p1 = exp2f(st[ct][1]);
        float p2 = exp2f(st[ct][2]), p3 = exp2f(st[ct][3]);
        ls += (p0 + p1) + (p2 + p3);
        u32 lo = (u32)f2bfh(p0) | ((u32)f2bfh(p1) << 16);
        u32 hi = (u32)f2bfh(p2) | ((u32)f2bfh(p3) << 16);
        *(u32x2*)(prow + ((ct * 32 + lg * 8) ^ swzP)) = (u32x2){lo, hi};
      }
      l_s[s] += ls;

      bf16x8 pa0 = *(const bf16x8*)(prow + ((lg * 16) ^ swzP));
      bf16x8 pa1 = *(const bf16x8*)(prow + ((64 + lg * 16) ^ swzP));

#pragma unroll
      for (int n = 0; n < 4; ++n) {
        acc[s][n] = __builtin_amdgcn_mfma_f32_16x16x32_bf16(pa0, vf[n][0], acc[s][n], 0, 0, 0);
        acc[s][n] = __builtin_amdgcn_mfma_f32_16x16x32_bf16(pa1, vf[n][1], acc[s][n], 0, 0, 0);
      }
    }
  }

#pragma unroll
  for (int s = 0; s < 2; ++s) {
    float lv = l_s[s];
    lv += __shfl_xor(lv, 16);
    lv += __shfl_xor(lv, 32);
    if (lg == 0) {
      int qrow = q0s[s] + w * 16 + l15;
      lP[((size_t)z * 4096 + b * 2048 + qrow) * 16 + h] = lv;
    }
#pragma unroll
    for (int i = 0; i < 4; ++i) {
      int srowg = q0s[s] + w * 16 + lg * 4 + i;
      size_t rowbase = (size_t)z * 4096 + b * 2048 + srowg;
      u16* orow = accP + rowbase * 1024 + h * 64 + l15;
#pragma unroll
      for (int n = 0; n < 4; ++n) orow[n * 16] = f2bfh(acc[s][n][i]);
    }
  }
}

// ---------------- combine + gate: O = (a0+a1)/(l0+l1) * sigmoid(x[:12]@gw[h]) ----------
__global__ __launch_bounds__(256) void attn_combine(const u16* __restrict__ accP, const float* __restrict__ lP,
                                                    const float* __restrict__ x, const float* __restrict__ gw,
                                                    u16* __restrict__ attnh) {
  const size_t e = ((size_t)blockIdx.x * 256 + threadIdx.x) * 8;
  const int token = (int)(e >> 10);
  const int h = (int)((e >> 6) & 15);
  u16x8 a0 = *(const u16x8*)(accP + e);
  u16x8 a1 = *(const u16x8*)(accP + ((size_t)4096 << 10) + e);
  const size_t li = (size_t)token * 16 + h;
  float l = lP[li] + lP[(size_t)4096 * 16 + li];
  float gd = 0.f;
#pragma unroll
  for (int j = 0; j < 12; ++j) gd += x[(size_t)token * 1024 + j] * gw[h * 12 + j];
  float g = (1.0f / (1.0f + __expf(-gd))) / l;
  u16x8 o;
#pragma unroll
  for (int j = 0; j < 8; ++j) o[j] = f2bfh((bf2f(a0[j]) + bf2f(a1[j])) * g);
  *(u16x8*)(attnh + e) = o;
}

// ---------------- launch ----------------
extern "C" void kernel_launch(void* const* d_in, const int* in_sizes, int n_in,
                              void* d_out, int out_size, void* d_ws, size_t ws_size,
                              hipStream_t stream) {
  const float* x  = (const float*)d_in[0];
  const float* Wf = (const float*)d_in[1];
  const float* qw = (const float*)d_in[2];
  const float* kw = (const float*)d_in[3];
  const float* gw = (const float*)d_in[4];
  float* out = (float*)d_out;

  char* ws = (char*)d_ws;
  size_t off = 0;
  auto alloc = [&](size_t bytes) { void* p = ws + off; off += (bytes + 255) & ~(size_t)255; return p; };

  u16*    xb   = (u16*)alloc((size_t)4096 * 1024 * 2);
  u16*    wb   = (u16*)alloc((size_t)2560 * 1024 * 2);
  float2* tab  = (float2*)alloc((size_t)2048 * 32 * 8);
  u16*    Qb   = (u16*)alloc((size_t)2 * 16 * 2048 * 64 * 2);
  u16*    Kb   = (u16*)alloc((size_t)2 * 4 * 2048 * 64 * 2);
  u16*    Vb   = (u16*)alloc((size_t)2 * 4 * 2048 * 64 * 2);
  u16*    Vtb  = (u16*)alloc((size_t)2 * 4 * 2048 * 64 * 2);
  float*  lP   = (float*)alloc((size_t)2 * 4096 * 16 * 4);
  u16*    accP = (u16*)alloc((size_t)2 * 4096 * 1024 * 2);
  // attnh aliases xb (dead after gemm_qkv)
  u16* attnh = xb;

  cvt2_bf16<<<dim3(6656), dim3(256), 0, stream>>>(x, xb, 4096 * 1024 / 4, Wf, wb, 2560 * 1024 / 4);
  rope_tab_k<<<dim3(256), dim3(256), 0, stream>>>(tab);
  gemm_qkv<<<dim3(64, 12), dim3(256), 0, stream>>>(xb, wb, qw, kw, tab, Qb, Kb, Vb, 1024);
  transpose_v64<<<dim3(32, 8), dim3(256), 0, stream>>>(Vb, Vtb);
  attn_fwd_pair<<<dim3(16, 32, 2), dim3(256), 0, stream>>>(Qb, Kb, Vtb, accP, lP);
  attn_combine<<<dim3(2048), dim3(256), 0, stream>>>(accP, lP, x, gw, attnh);
  gemm_nt<<<dim3(64, 8), dim3(256), 0, stream>>>(attnh, wb + (size_t)1536 * 1024, out, 4096, 1024, 1024);
}

// Round 17
// 112.781 us; speedup vs baseline: 1.3218x; 1.0268x over previous
//
#include <hip/hip_runtime.h>
#include <math.h>

typedef unsigned short u16;
typedef unsigned int u32;
typedef __bf16 bf16x8 __attribute__((ext_vector_type(8)));
typedef float f32x4 __attribute__((ext_vector_type(4)));
typedef unsigned short u16x8 __attribute__((ext_vector_type(8)));
typedef unsigned int u32x2 __attribute__((ext_vector_type(2)));

static __device__ __forceinline__ u16 f2bf(float f) {
  unsigned int u = __builtin_bit_cast(unsigned int, f);
  u = (u + 0x7FFFu + ((u >> 16) & 1u)) >> 16;
  return (u16)u;
}
static __device__ __forceinline__ float bf2f(u16 u) {
  unsigned int x = ((unsigned int)u) << 16;
  return __builtin_bit_cast(float, x);
}
static __device__ __forceinline__ u16 f2bfh(float f) {
  __bf16 b = (__bf16)f;
  return __builtin_bit_cast(u16, b);
}
static __device__ __forceinline__ void gll16(const u16* g, u16* l) {
  __builtin_amdgcn_global_load_lds((const __attribute__((address_space(1))) u32*)g,
                                   (__attribute__((address_space(3))) u32*)l, 16, 0, 0);
}

#define QSCALE 0.18033688011112042f

// ---------------- prep: f32->bf16 for x and W + RoPE cos/sin table (disjoint ranges) ----
__global__ __launch_bounds__(256) void prep_k(const float* __restrict__ a, u16* __restrict__ da, int n4a,
                                              const float* __restrict__ b, u16* __restrict__ db, int n4b,
                                              float2* __restrict__ tab) {
  int idx = blockIdx.x * 256 + threadIdx.x;
  if (idx < n4a + n4b) {
    const float* src; u16* dst; int i;
    if (idx < n4a) { src = a; dst = da; i = idx; }
    else { src = b; dst = db; i = idx - n4a; }
    float4 v = ((const float4*)src)[i];
    ushort4 r;
    r.x = f2bf(v.x); r.y = f2bf(v.y); r.z = f2bf(v.z); r.w = f2bf(v.w);
    ((ushort4*)dst)[i] = r;
  } else {
    int e = idx - n4a - n4b;
    if (e < 2048 * 32) {
      int s = e >> 5, j = e & 31;
      float sn, cs;
      sincosf((float)s * expf(-(float)j * (9.21034037198f / 32.0f)), &sn, &cs);
      tab[e] = make_float2(cs, sn);
    }
  }
}

// ---------------- bf16 NT GEMM, 64x128 tile (out-proj): gll16 staging ----------------
__global__ __launch_bounds__(256) void gemm_nt(const u16* __restrict__ A, const u16* __restrict__ B,
                                               float* __restrict__ C, int M, int N, int K) {
  __shared__ __align__(16) u16 sA[64 * 32];
  __shared__ __align__(16) u16 sB[128 * 32];
  const int tid = threadIdx.x;
  const int w = tid >> 6, lane = tid & 63, l15 = lane & 15;
  const int m0 = blockIdx.x * 64, n0 = blockIdx.y * 128;
  const int wm = (w >> 1) * 32, wn = (w & 1) * 64;

  f32x4 acc[2][4] = {};

  int sArow, sAcol;
  {
    int p = tid * 16;
    int row = p >> 6, oo = p & 63;
    int ol = oo ^ (((row >> 1) & 3) << 4);
    sArow = row; sAcol = ol >> 1;
  }
  int sBrow[2], sBcol[2];
#pragma unroll
  for (int i = 0; i < 2; ++i) {
    int p = i * 4096 + tid * 16;
    int row = p >> 6, oo = p & 63;
    int ol = oo ^ (((row >> 1) & 3) << 4);
    sBrow[i] = row; sBcol[i] = ol >> 1;
  }
  int aoff[2], boff[4];
  const int kb = (lane >> 4) * 16;
#pragma unroll
  for (int m = 0; m < 2; ++m) {
    int r = wm + m * 16 + l15;
    aoff[m] = r * 64 + (kb ^ (((r >> 1) & 3) << 4));
  }
#pragma unroll
  for (int n = 0; n < 4; ++n) {
    int r = wn + n * 16 + l15;
    boff[n] = r * 64 + (kb ^ (((r >> 1) & 3) << 4));
  }

  for (int k0 = 0; k0 < K; k0 += 32) {
    gll16(A + (size_t)(m0 + sArow) * K + k0 + sAcol, (u16*)((char*)sA + tid * 16));
#pragma unroll
    for (int i = 0; i < 2; ++i)
      gll16(B + (size_t)(n0 + sBrow[i]) * K + k0 + sBcol[i], (u16*)((char*)sB + i * 4096 + tid * 16));
    __syncthreads();
    bf16x8 af[2], bfr[4];
#pragma unroll
    for (int m = 0; m < 2; ++m) af[m] = *(const bf16x8*)((const char*)sA + aoff[m]);
#pragma unroll
    for (int n = 0; n < 4; ++n) bfr[n] = *(const bf16x8*)((const char*)sB + boff[n]);
#pragma unroll
    for (int m = 0; m < 2; ++m)
#pragma unroll
      for (int n = 0; n < 4; ++n)
        acc[m][n] = __builtin_amdgcn_mfma_f32_16x16x32_bf16(af[m], bfr[n], acc[m][n], 0, 0, 0);
    __syncthreads();
  }

#pragma unroll
  for (int m = 0; m < 2; ++m)
#pragma unroll
    for (int i = 0; i < 4; ++i) {
      int gr = m0 + wm + m * 16 + (lane >> 4) * 4 + i;
      float* crow = C + (size_t)gr * N + n0 + wn + l15;
#pragma unroll
      for (int n = 0; n < 4; ++n) crow[n * 16] = acc[m][n][i];
    }
}

// ---------------- QKV GEMM (64x128 tile), fused RMSNorm+RoPE; V written TRANSPOSED ----
// Wave tile 32 x 64: one wave spans exactly one head; he = (n0+wn)>>6 in 0..23.
// he<16 -> Q (norm+rope, *QSCALE); he<20 -> K (norm+rope); else V -> Vt[bh][d][s].
__global__ __launch_bounds__(256) void gemm_qkv(const u16* __restrict__ A, const u16* __restrict__ B,
                                                const float* __restrict__ qw, const float* __restrict__ kw,
                                                const float2* __restrict__ tab,
                                                u16* __restrict__ Qo, u16* __restrict__ Ko,
                                                u16* __restrict__ Vt, int K) {
  __shared__ __align__(16) u16 sA[64 * 32];
  __shared__ __align__(16) u16 sB[128 * 32];
  const int tid = threadIdx.x;
  const int w = tid >> 6, lane = tid & 63, l15 = lane & 15, lg = lane >> 4;
  const int m0 = blockIdx.x * 64, n0 = blockIdx.y * 128;
  const int wm = (w >> 1) * 32, wn = (w & 1) * 64;

  f32x4 acc[2][4] = {};

  int sArow, sAcol;
  {
    int p = tid * 16;
    int row = p >> 6, oo = p & 63;
    int ol = oo ^ (((row >> 1) & 3) << 4);
    sArow = row; sAcol = ol >> 1;
  }
  int sBrow[2], sBcol[2];
#pragma unroll
  for (int i = 0; i < 2; ++i) {
    int p = i * 4096 + tid * 16;
    int row = p >> 6, oo = p & 63;
    int ol = oo ^ (((row >> 1) & 3) << 4);
    sBrow[i] = row; sBcol[i] = ol >> 1;
  }
  int aoff[2], boff[4];
  const int kb = lg * 16;
#pragma unroll
  for (int m = 0; m < 2; ++m) {
    int r = wm + m * 16 + l15;
    aoff[m] = r * 64 + (kb ^ (((r >> 1) & 3) << 4));
  }
#pragma unroll
  for (int n = 0; n < 4; ++n) {
    int r = wn + n * 16 + l15;
    boff[n] = r * 64 + (kb ^ (((r >> 1) & 3) << 4));
  }

  for (int k0 = 0; k0 < K; k0 += 32) {
    gll16(A + (size_t)(m0 + sArow) * K + k0 + sAcol, (u16*)((char*)sA + tid * 16));
#pragma unroll
    for (int i = 0; i < 2; ++i)
      gll16(B + (size_t)(n0 + sBrow[i]) * K + k0 + sBcol[i], (u16*)((char*)sB + i * 4096 + tid * 16));
    __syncthreads();
    bf16x8 af[2], bfr[4];
#pragma unroll
    for (int m = 0; m < 2; ++m) af[m] = *(const bf16x8*)((const char*)sA + aoff[m]);
#pragma unroll
    for (int n = 0; n < 4; ++n) bfr[n] = *(const bf16x8*)((const char*)sB + boff[n]);
#pragma unroll
    for (int m = 0; m < 2; ++m)
#pragma unroll
      for (int n = 0; n < 4; ++n)
        acc[m][n] = __builtin_amdgcn_mfma_f32_16x16x32_bf16(af[m], bfr[n], acc[m][n], 0, 0, 0);
    __syncthreads();
  }

  const int he = (n0 + wn) >> 6;   // wave-uniform head index 0..23
  if (he < 20) {
    const float* wnorm = (he < 16) ? qw : kw;
    const float oscale = (he < 16) ? QSCALE : 1.0f;
    float wv[4];
#pragma unroll
    for (int n = 0; n < 4; ++n) wv[n] = wnorm[n * 16 + l15];
    float2 tj[4];
#pragma unroll
    for (int m = 0; m < 2; ++m)
#pragma unroll
      for (int i = 0; i < 4; ++i) {
        const int gr = m0 + wm + m * 16 + lg * 4 + i;
        const int s = gr & 2047, bb = gr >> 11;
        float ss = 0.f;
#pragma unroll
        for (int n = 0; n < 4; ++n) ss += acc[m][n][i] * acc[m][n][i];
        ss += __shfl_xor(ss, 8); ss += __shfl_xor(ss, 4);
        ss += __shfl_xor(ss, 2); ss += __shfl_xor(ss, 1);
        const float r = rsqrtf(ss * (1.0f / 64.0f) + 1.1920929e-7f);
#pragma unroll
        for (int n = 0; n < 4; ++n) tj[n] = tab[s * 32 + n * 8 + (l15 >> 1)];
        u16* orow = (he < 16)
          ? Qo + ((size_t)(bb * 16 + he) * 2048 + s) * 64 + l15
          : Ko + ((size_t)(bb * 4 + (he - 16)) * 2048 + s) * 64 + l15;
#pragma unroll
        for (int n = 0; n < 4; ++n) {
          float xn = acc[m][n][i] * r * wv[n];
          float p = __shfl_xor(xn, 1);
          float outv = ((l15 & 1) == 0) ? (xn * tj[n].x - p * tj[n].y)
                                        : (xn * tj[n].x + p * tj[n].y);
          orow[n * 16] = f2bf(outv * oscale);
        }
      }
  } else {
    // V: write transposed Vt[bh][d][s] directly (scatter u16 stores; 2/12 of blocks)
#pragma unroll
    for (int m = 0; m < 2; ++m)
#pragma unroll
      for (int i = 0; i < 4; ++i) {
        const int gr = m0 + wm + m * 16 + lg * 4 + i;
        const int s = gr & 2047, bb = gr >> 11;
        u16* vcol = Vt + ((size_t)(bb * 4 + (he - 20)) * 64 + l15) * 2048 + s;
#pragma unroll
        for (int n = 0; n < 4; ++n) vcol[(size_t)n * 16 * 2048] = f2bf(acc[m][n][i]);
      }
  }
}

// ---------------- Flash attention: r15 body (paired q-tiles + KV-parity, 24.5 KB LDS) ----
__global__ __launch_bounds__(256) void attn_fwd_pair(const u16* __restrict__ Q, const u16* __restrict__ Kg,
                                                     const u16* __restrict__ Vt,
                                                     u16* __restrict__ accP, float* __restrict__ lP) {
  __shared__ __align__(16) u16 sK[64 * 64];
  __shared__ __align__(16) u16 sV[64 * 64];
  __shared__ __align__(16) u16 sP[4][16 * 64];

  const int tid = threadIdx.x;
  const int w = tid >> 6, lane = tid & 63;
  const int l15 = lane & 15, lg = lane >> 4;
  const int qiA = blockIdx.x;
  const int qiB = 31 - qiA;
  const int z = blockIdx.z;
  const int bh = blockIdx.y, b = bh >> 4, h = bh & 15, kvh = h >> 2;

  const u16* Qp = Q + (size_t)(b * 16 + h) * 2048 * 64;
  const u16* Kp = Kg + (size_t)(b * 4 + kvh) * 2048 * 64;
  const u16* Vp = Vt + (size_t)(b * 4 + kvh) * 64 * 2048;

  const int q0s[2] = {qiA * 64, qiB * 64};
  bf16x8 qa[2][2];
#pragma unroll
  for (int s = 0; s < 2; ++s) {
    const u16* qrow = Qp + (size_t)(q0s[s] + w * 16 + l15) * 64 + lg * 8;
    qa[s][0] = *(const bf16x8*)qrow;
    qa[s][1] = *(const bf16x8*)(qrow + 32);
  }

  f32x4 acc[2][4] = {};
  float l_s[2] = {0.f, 0.f};

  const int srw = tid >> 2;
  const int scb = (tid & 3) * 32;
  const int swzS = (srw & 7) << 4;
  const int st0 = srw * 128 + (scb ^ swzS);
  const int st1 = srw * 128 + ((scb + 16) ^ swzS);
  const u16* kgp = Kp + (size_t)srw * 64 + (tid & 3) * 16;
  const u16* vgp = Vp + (size_t)srw * 2048 + (tid & 3) * 16;

  const int swzF = (l15 & 7) << 4;
  const int fo0 = (lg * 16) ^ swzF;
  const int fo1 = (64 + lg * 16) ^ swzF;

  u16x8 kr0 = *(const u16x8*)(kgp + (size_t)z * 64 * 64), kr1 = *(const u16x8*)(kgp + (size_t)z * 64 * 64 + 8);
  u16x8 vr0 = *(const u16x8*)(vgp + z * 64),              vr1 = *(const u16x8*)(vgp + z * 64 + 8);

  for (int t = z; t <= qiB; t += 2) {
    __syncthreads();
    *(u16x8*)((char*)sK + st0) = kr0; *(u16x8*)((char*)sK + st1) = kr1;
    *(u16x8*)((char*)sV + st0) = vr0; *(u16x8*)((char*)sV + st1) = vr1;
    __syncthreads();

    if (t + 2 <= qiB) {
      const u16* kg = kgp + (size_t)(t + 2) * 64 * 64;
      const u16* vg = vgp + (t + 2) * 64;
      kr0 = *(const u16x8*)kg; kr1 = *(const u16x8*)(kg + 8);
      vr0 = *(const u16x8*)vg; vr1 = *(const u16x8*)(vg + 8);
    }

    bf16x8 kf[4][2], vf[4][2];
#pragma unroll
    for (int ct = 0; ct < 4; ++ct) {
      const char* krow = (const char*)sK + (ct * 16 + l15) * 128;
      const char* vrow = (const char*)sV + (ct * 16 + l15) * 128;
      kf[ct][0] = *(const bf16x8*)(krow + fo0);
      kf[ct][1] = *(const bf16x8*)(krow + fo1);
      vf[ct][0] = *(const bf16x8*)(vrow + fo0);
      vf[ct][1] = *(const bf16x8*)(vrow + fo1);
    }

#pragma unroll
    for (int s = 0; s < 2; ++s) {
      if (s == 0 && t > qiA) continue;
      const int diag = s ? qiB : qiA;

      f32x4 st[4];
#pragma unroll
      for (int ct = 0; ct < 4; ++ct) {
        f32x4 s4 = {};
        s4 = __builtin_amdgcn_mfma_f32_16x16x32_bf16(kf[ct][0], qa[s][0], s4, 0, 0, 0);
        s4 = __builtin_amdgcn_mfma_f32_16x16x32_bf16(kf[ct][1], qa[s][1], s4, 0, 0, 0);
        st[ct] = s4;
      }

      if (t == diag) {
        const int ql = w * 16 + l15;
#pragma unroll
        for (int ct = 0; ct < 4; ++ct)
#pragma unroll
          for (int i = 0; i < 4; ++i)
            st[ct][i] = (ct * 16 + lg * 4 + i <= ql) ? st[ct][i] : -1e30f;
      }

      float ls = 0.f;
      const int swzP = (l15 & 7) << 4;
      char* prow = (char*)sP[w] + l15 * 128;
#pragma unroll
      for (int ct = 0; ct < 4; ++ct) {
        float p0 = exp2f(st[ct][0]), p1 = exp2f(st[ct][1]);
        float p2 = exp2f(st[ct][2]), p3 = exp2f(st[ct][3]);
        ls += (p0 + p1) + (p2 + p3);
        u32 lo = (u32)f2bfh(p0) | ((u32)f2bfh(p1) << 16);
        u32 hi = (u32)f2bfh(p2) | ((u32)f2bfh(p3) << 16);
        *(u32x2*)(prow + ((ct * 32 + lg * 8) ^ swzP)) = (u32x2){lo, hi};
      }
      l_s[s] += ls;

      bf16x8 pa0 = *(const bf16x8*)(prow + ((lg * 16) ^ swzP));
      bf16x8 pa1 = *(const bf16x8*)(prow + ((64 + lg * 16) ^ swzP));

#pragma unroll
      for (int n = 0; n < 4; ++n) {
        acc[s][n] = __builtin_amdgcn_mfma_f32_16x16x32_bf16(pa0, vf[n][0], acc[s][n], 0, 0, 0);
        acc[s][n] = __builtin_amdgcn_mfma_f32_16x16x32_bf16(pa1, vf[n][1], acc[s][n], 0, 0, 0);
      }
    }
  }

#pragma unroll
  for (int s = 0; s < 2; ++s) {
    float lv = l_s[s];
    lv += __shfl_xor(lv, 16);
    lv += __shfl_xor(lv, 32);
    if (lg == 0) {
      int qrow = q0s[s] + w * 16 + l15;
      lP[((size_t)z * 4096 + b * 2048 + qrow) * 16 + h] = lv;
    }
#pragma unroll
    for (int i = 0; i < 4; ++i) {
      int srowg = q0s[s] + w * 16 + lg * 4 + i;
      size_t rowbase = (size_t)z * 4096 + b * 2048 + srowg;
      u16* orow = accP + rowbase * 1024 + h * 64 + l15;
#pragma unroll
      for (int n = 0; n < 4; ++n) orow[n * 16] = f2bfh(acc[s][n][i]);
    }
  }
}

// ---------------- combine + gate: O = (a0+a1)/(l0+l1) * sigmoid(x[:12]@gw[h]) ----------
__global__ __launch_bounds__(256) void attn_combine(const u16* __restrict__ accP, const float* __restrict__ lP,
                                                    const float* __restrict__ x, const float* __restrict__ gw,
                                                    u16* __restrict__ attnh) {
  const size_t e = ((size_t)blockIdx.x * 256 + threadIdx.x) * 8;
  const int token = (int)(e >> 10);
  const int h = (int)((e >> 6) & 15);
  u16x8 a0 = *(const u16x8*)(accP + e);
  u16x8 a1 = *(const u16x8*)(accP + ((size_t)4096 << 10) + e);
  const size_t li = (size_t)token * 16 + h;
  float l = lP[li] + lP[(size_t)4096 * 16 + li];
  float gd = 0.f;
#pragma unroll
  for (int j = 0; j < 12; ++j) gd += x[(size_t)token * 1024 + j] * gw[h * 12 + j];
  float g = (1.0f / (1.0f + __expf(-gd))) / l;
  u16x8 o;
#pragma unroll
  for (int j = 0; j < 8; ++j) o[j] = f2bfh((bf2f(a0[j]) + bf2f(a1[j])) * g);
  *(u16x8*)(attnh + e) = o;
}

// ---------------- launch ----------------
extern "C" void kernel_launch(void* const* d_in, const int* in_sizes, int n_in,
                              void* d_out, int out_size, void* d_ws, size_t ws_size,
                              hipStream_t stream) {
  const float* x  = (const float*)d_in[0];
  const float* Wf = (const float*)d_in[1];
  const float* qw = (const float*)d_in[2];
  const float* kw = (const float*)d_in[3];
  const float* gw = (const float*)d_in[4];
  float* out = (float*)d_out;

  char* ws = (char*)d_ws;
  size_t off = 0;
  auto alloc = [&](size_t bytes) { void* p = ws + off; off += (bytes + 255) & ~(size_t)255; return p; };

  u16*    xb   = (u16*)alloc((size_t)4096 * 1024 * 2);
  u16*    wb   = (u16*)alloc((size_t)2560 * 1024 * 2);
  float2* tab  = (float2*)alloc((size_t)2048 * 32 * 8);
  u16*    Qb   = (u16*)alloc((size_t)2 * 16 * 2048 * 64 * 2);
  u16*    Kb   = (u16*)alloc((size_t)2 * 4 * 2048 * 64 * 2);
  u16*    Vtb  = (u16*)alloc((size_t)2 * 4 * 2048 * 64 * 2);
  float*  lP   = (float*)alloc((size_t)2 * 4096 * 16 * 4);
  u16*    accP = (u16*)alloc((size_t)2 * 4096 * 1024 * 2);
  // attnh aliases xb (dead after gemm_qkv)
  u16* attnh = xb;

  const int n4a = 4096 * 1024 / 4, n4b = 2560 * 1024 / 4;
  const int prep_total = n4a + n4b + 2048 * 32;
  prep_k<<<dim3((prep_total + 255) / 256), dim3(256), 0, stream>>>(x, xb, n4a, Wf, wb, n4b, tab);
  gemm_qkv<<<dim3(64, 12), dim3(256), 0, stream>>>(xb, wb, qw, kw, tab, Qb, Kb, Vtb, 1024);
  attn_fwd_pair<<<dim3(16, 32, 2), dim3(256), 0, stream>>>(Qb, Kb, Vtb, accP, lP);
  attn_combine<<<dim3(2048), dim3(256), 0, stream>>>(accP, lP, x, gw, attnh);
  gemm_nt<<<dim3(64, 8), dim3(256), 0, stream>>>(attnh, wb + (size_t)1536 * 1024, out, 4096, 1024, 1024);
}